// Round 8
// baseline (456.231 us; speedup 1.0000x reference)
//
#include <hip/hip_runtime.h>
#include <hip/hip_fp16.h>
#include <math.h>

#define RRELU_SLOPE 0.22916667f  // (1/8 + 1/3)/2 = 11/48

// ---------------------------------------------------------------------------
// CSR build: zero -> histogram(+rank) -> scan -> rank-based scatter.
// Plus degree-descending node order (counting sort) for agg load balance.
// ---------------------------------------------------------------------------

__global__ __launch_bounds__(256) void k_zero(int* __restrict__ cnt, int N,
                                              int* __restrict__ dh,
                                              int* __restrict__ dp) {
    int i = blockIdx.x * 256 + threadIdx.x;
    if (i < N) cnt[i] = 0;
    if (blockIdx.x == 0 && threadIdx.x < 64) {
        dh[threadIdx.x] = 0;
        dp[threadIdx.x] = 0;
    }
}

__global__ __launch_bounds__(256) void k_deg(const int* __restrict__ dst, int E,
                                             int* __restrict__ cnt,
                                             int* __restrict__ rank) {
    int e = blockIdx.x * 256 + threadIdx.x;
    if (e < E) rank[e] = atomicAdd(&cnt[dst[e]], 1);
}

__global__ __launch_bounds__(256) void k_scan1(const int* __restrict__ cnt, int N,
                                               int* __restrict__ bsum) {
    int i = blockIdx.x * 256 + threadIdx.x;
    int v = (i < N) ? cnt[i] : 0;
    for (int o = 32; o >= 1; o >>= 1) v += __shfl_xor(v, o, 64);
    __shared__ int ws[4];
    if ((threadIdx.x & 63) == 0) ws[threadIdx.x >> 6] = v;
    __syncthreads();
    if (threadIdx.x == 0) bsum[blockIdx.x] = ws[0] + ws[1] + ws[2] + ws[3];
}

__global__ __launch_bounds__(256) void k_scan2(const int* __restrict__ bsum, int NB,
                                               int* __restrict__ boff,
                                               int* __restrict__ rowp, int N, int E) {
    __shared__ int s[256];
    int t = threadIdx.x;
    int v[4];
    int loc = 0;
    for (int i = 0; i < 4; i++) {
        int idx = t * 4 + i;
        v[i] = (idx < NB) ? bsum[idx] : 0;
        loc += v[i];
    }
    s[t] = loc;
    __syncthreads();
    for (int o = 1; o < 256; o <<= 1) {
        int u = (t >= o) ? s[t - o] : 0;
        __syncthreads();
        s[t] += u;
        __syncthreads();
    }
    int excl = s[t] - loc;
    for (int i = 0; i < 4; i++) {
        int idx = t * 4 + i;
        if (idx < NB) { boff[idx] = excl; excl += v[i]; }
    }
    if (t == 0) rowp[N] = E;
}

__global__ __launch_bounds__(256) void k_scan3(const int* __restrict__ cnt,
                                               const int* __restrict__ boff, int N,
                                               int* __restrict__ rowp,
                                               float* __restrict__ dinv,
                                               int* __restrict__ dh) {
    int i = blockIdx.x * 256 + threadIdx.x;
    int lane = threadIdx.x & 63, wid = threadIdx.x >> 6;
    int v = (i < N) ? cnt[i] : 0;
    int inc = v;
    for (int o = 1; o < 64; o <<= 1) {
        int u = __shfl_up(inc, o, 64);
        if (lane >= o) inc += u;
    }
    __shared__ int wsum[4];
    if (lane == 63) wsum[wid] = inc;
    __syncthreads();
    int wo = 0;
    for (int w = 0; w < wid; w++) wo += wsum[w];
    if (i < N) {
        int excl = inc - v + wo + boff[blockIdx.x];
        rowp[i] = excl;
        dinv[i] = 1.0f / sqrtf((float)v + 1.0f);
        atomicAdd(&dh[min(v, 63)], 1);
    }
}

// exclusive offsets for degree buckets, DESCENDING (bucket 63 first)
__global__ void k_dscan(const int* __restrict__ dh, int* __restrict__ doff) {
    int l = threadIdx.x;  // 0..63
    int v = dh[63 - l];
    int inc = v;
    for (int o = 1; o < 64; o <<= 1) {
        int u = __shfl_up(inc, o, 64);
        if (l >= o) inc += u;
    }
    doff[63 - l] = inc - v;
}

__global__ __launch_bounds__(256) void k_order(const int* __restrict__ cnt,
                                               const int* __restrict__ doff,
                                               int* __restrict__ dpos,
                                               int* __restrict__ order, int N) {
    int i = blockIdx.x * 256 + threadIdx.x;
    if (i >= N) return;
    int d = min(cnt[i], 63);
    int r = atomicAdd(&dpos[d], 1);
    order[doff[d] + r] = i;
}

__global__ __launch_bounds__(256) void k_fill(const int* __restrict__ src,
                                              const int* __restrict__ dst,
                                              const int* __restrict__ rank, int E,
                                              const int* __restrict__ rowp,
                                              int* __restrict__ csrc) {
    int e = blockIdx.x * 256 + threadIdx.x;
    if (e >= E) return;
    int d = dst[e];
    csrc[rowp[d] + rank[e]] = src[e];
}

// ---------------------------------------------------------------------------
// Layer-1 matmul (f32 A, K=128), one branch per block (blockIdx.y):
// Hh' = fp16(dinv[r] * (A @ W)). 64x64 tile, 4x4 register micro-kernel.
// ---------------------------------------------------------------------------
__global__ __launch_bounds__(256) void k_mm1(const float* __restrict__ A0,
                                             const float* __restrict__ A1,
                                             const float* __restrict__ W0,
                                             const float* __restrict__ W1,
                                             const float* __restrict__ dinv,
                                             __half* __restrict__ Hh, int N) {
    const float* A = blockIdx.y ? A1 : A0;
    const float* W = blockIdx.y ? W1 : W0;
    __half* H = Hh + (size_t)blockIdx.y * N * 64;

    __shared__ float As[64][20];
    __shared__ float Ws[16][64];

    const int tid = threadIdx.x;
    const int tc = tid & 15, tr = tid >> 4;
    const int row0 = blockIdx.x * 64;
    const int srow = tid >> 2, sk = (tid & 3) * 4;
    const int wk = tid >> 4, wc = (tid & 15) * 4;

    float acc[4][4] = {};

    for (int k0 = 0; k0 < 128; k0 += 16) {
        float4 av = make_float4(0.f, 0.f, 0.f, 0.f);
        int gr = row0 + srow;
        if (gr < N) av = *(const float4*)(A + (size_t)gr * 128 + k0 + sk);
        float4 wv = *(const float4*)(W + (size_t)(k0 + wk) * 64 + wc);
        __syncthreads();
        *(float4*)&As[srow][sk] = av;
        *(float4*)&Ws[wk][wc] = wv;
        __syncthreads();

#pragma unroll
        for (int k = 0; k < 16; k += 4) {
            float4 a4[4], w4[4];
#pragma unroll
            for (int i = 0; i < 4; i++) a4[i] = *(const float4*)&As[tr * 4 + i][k];
#pragma unroll
            for (int kk = 0; kk < 4; kk++) w4[kk] = *(const float4*)&Ws[k + kk][tc * 4];
#pragma unroll
            for (int i = 0; i < 4; i++) {
                const float* ap = (const float*)&a4[i];
#pragma unroll
                for (int kk = 0; kk < 4; kk++) {
                    const float* wp = (const float*)&w4[kk];
                    float a = ap[kk];
                    acc[i][0] = fmaf(a, wp[0], acc[i][0]);
                    acc[i][1] = fmaf(a, wp[1], acc[i][1]);
                    acc[i][2] = fmaf(a, wp[2], acc[i][2]);
                    acc[i][3] = fmaf(a, wp[3], acc[i][3]);
                }
            }
        }
    }

#pragma unroll
    for (int i = 0; i < 4; i++) {
        int r = row0 + tr * 4 + i;
        if (r < N) {
            float dv = dinv[r];
            union { __half2 h2[2]; uint2 u; } pk;
            pk.h2[0] = __floats2half2_rn(acc[i][0] * dv, acc[i][1] * dv);
            pk.h2[1] = __floats2half2_rn(acc[i][2] * dv, acc[i][3] * dv);
            *(uint2*)(H + (size_t)r * 64 + tc * 4) = pk.u;
        }
    }
}

// ---------------------------------------------------------------------------
// Layer-2 matmul: fp16 A planes (K=64), f32 W; fp16 output like k_mm1.
// fp16 A staged to LDS as f32.
// ---------------------------------------------------------------------------
__global__ __launch_bounds__(256) void k_mm2h(const __half* __restrict__ A0,
                                              const __half* __restrict__ A1,
                                              const float* __restrict__ W0,
                                              const float* __restrict__ W1,
                                              const float* __restrict__ dinv,
                                              __half* __restrict__ Hh, int N) {
    const __half* A = blockIdx.y ? A1 : A0;
    const float* W = blockIdx.y ? W1 : W0;
    __half* H = Hh + (size_t)blockIdx.y * N * 64;

    __shared__ float As[64][20];
    __shared__ float Ws[16][64];

    const int tid = threadIdx.x;
    const int tc = tid & 15, tr = tid >> 4;
    const int row0 = blockIdx.x * 64;
    const int srow = tid >> 2, sk = (tid & 3) * 4;
    const int wk = tid >> 4, wc = (tid & 15) * 4;

    float acc[4][4] = {};

    for (int k0 = 0; k0 < 64; k0 += 16) {
        float4 av = make_float4(0.f, 0.f, 0.f, 0.f);
        int gr = row0 + srow;
        if (gr < N) {
            union { uint2 u; __half2 h2[2]; } cu;
            cu.u = *(const uint2*)(A + (size_t)gr * 64 + k0 + sk);
            float2 f01 = __half22float2(cu.h2[0]);
            float2 f23 = __half22float2(cu.h2[1]);
            av = make_float4(f01.x, f01.y, f23.x, f23.y);
        }
        float4 wv = *(const float4*)(W + (size_t)(k0 + wk) * 64 + wc);
        __syncthreads();
        *(float4*)&As[srow][sk] = av;
        *(float4*)&Ws[wk][wc] = wv;
        __syncthreads();

#pragma unroll
        for (int k = 0; k < 16; k += 4) {
            float4 a4[4], w4[4];
#pragma unroll
            for (int i = 0; i < 4; i++) a4[i] = *(const float4*)&As[tr * 4 + i][k];
#pragma unroll
            for (int kk = 0; kk < 4; kk++) w4[kk] = *(const float4*)&Ws[k + kk][tc * 4];
#pragma unroll
            for (int i = 0; i < 4; i++) {
                const float* ap = (const float*)&a4[i];
#pragma unroll
                for (int kk = 0; kk < 4; kk++) {
                    const float* wp = (const float*)&w4[kk];
                    float a = ap[kk];
                    acc[i][0] = fmaf(a, wp[0], acc[i][0]);
                    acc[i][1] = fmaf(a, wp[1], acc[i][1]);
                    acc[i][2] = fmaf(a, wp[2], acc[i][2]);
                    acc[i][3] = fmaf(a, wp[3], acc[i][3]);
                }
            }
        }
    }

#pragma unroll
    for (int i = 0; i < 4; i++) {
        int r = row0 + tr * 4 + i;
        if (r < N) {
            float dv = dinv[r];
            union { __half2 h2[2]; uint2 u; } pk;
            pk.h2[0] = __floats2half2_rn(acc[i][0] * dv, acc[i][1] * dv);
            pk.h2[1] = __floats2half2_rn(acc[i][2] * dv, acc[i][3] * dv);
            *(uint2*)(H + (size_t)r * 64 + tc * 4) = pk.u;
        }
    }
}

// ---------------------------------------------------------------------------
// Aggregation over pre-scaled fp16 planes, degree-sorted node order.
// 1 wave/node: lanes 0-31 = z plane, 32-63 = x plane. Pure gather+add,
// 8 edges in flight, 4 chains, f32 accumulation.
// ---------------------------------------------------------------------------
#define AGG_EDGE(S, C)                                   \
    {                                                    \
        float2 h_ = __half22float2(Hp[(size_t)(C) * 32]);\
        S.x += h_.x;                                     \
        S.y += h_.y;                                     \
    }

#define AGG_LOOP()                                                       \
    int beg = rowp[i], end = rowp[i + 1];                                \
    float2 s0 = {0.f, 0.f}, s1 = {0.f, 0.f}, s2 = {0.f, 0.f},            \
           s3 = {0.f, 0.f};                                              \
    int p = beg;                                                         \
    while (p < end && (p & 3)) { int c = csrc[p++]; AGG_EDGE(s0, c); }   \
    for (; p + 8 <= end; p += 8) {                                       \
        int4 ca = *(const int4*)(csrc + p);                              \
        int4 cb = *(const int4*)(csrc + p + 4);                          \
        AGG_EDGE(s0, ca.x); AGG_EDGE(s1, ca.y);                          \
        AGG_EDGE(s2, ca.z); AGG_EDGE(s3, ca.w);                          \
        AGG_EDGE(s0, cb.x); AGG_EDGE(s1, cb.y);                          \
        AGG_EDGE(s2, cb.z); AGG_EDGE(s3, cb.w);                          \
    }                                                                    \
    if (p + 4 <= end) {                                                  \
        int4 ca = *(const int4*)(csrc + p);                              \
        AGG_EDGE(s0, ca.x); AGG_EDGE(s1, ca.y);                          \
        AGG_EDGE(s2, ca.z); AGG_EDGE(s3, ca.w);                          \
        p += 4;                                                          \
    }                                                                    \
    while (p < end) { int c = csrc[p++]; AGG_EDGE(s0, c); }

__global__ __launch_bounds__(256) void k_agg_act(
    const int* __restrict__ order, const int* __restrict__ rowp,
    const int* __restrict__ csrc, const float* __restrict__ dinv,
    const __half2* __restrict__ H2, int N, const float* __restrict__ bz,
    const float* __restrict__ bx, __half* __restrict__ azh,
    __half* __restrict__ axh) {
    int wid = threadIdx.x >> 6, lane = threadIdx.x & 63;
    int idx = blockIdx.x * 4 + wid;
    if (idx >= N) return;
    int i = order[idx];
    int j = lane & 31;
    const __half2* Hp = H2 + (size_t)(lane >> 5) * N * 32 + j;
    AGG_LOOP();

    float2 hs = __half22float2(Hp[(size_t)i * 32]);
    float sumx = ((s0.x + s1.x) + (s2.x + s3.x)) + hs.x;
    float sumy = ((s0.y + s1.y) + (s2.y + s3.y)) + hs.y;
    float dvi = dinv[i];
    const float* bb = (lane >= 32) ? bx : bz;
    float2 b = *(const float2*)(bb + 2 * j);
    float f0 = fmaf(dvi, sumx, b.x);
    float f1 = fmaf(dvi, sumy, b.y);
    f0 = f0 >= 0.f ? f0 : f0 * RRELU_SLOPE;
    f1 = f1 >= 0.f ? f1 : f1 * RRELU_SLOPE;
    __half* ap = (lane >= 32) ? axh : azh;
    ((__half2*)ap)[(size_t)i * 32 + j] = __floats2half2_rn(f0, f1);
}

__global__ __launch_bounds__(256) void k_agg_final(
    const int* __restrict__ order, const int* __restrict__ rowp,
    const int* __restrict__ csrc, const float* __restrict__ dinv,
    const __half2* __restrict__ H2, int N, const float* __restrict__ bz,
    const float* __restrict__ bx, const float* __restrict__ Wout,
    const float* __restrict__ bout, float* __restrict__ out) {
    int wid = threadIdx.x >> 6, lane = threadIdx.x & 63;
    int idx = blockIdx.x * 4 + wid;
    if (idx >= N) return;
    int i = order[idx];
    int j = lane & 31;
    const __half2* Hp = H2 + (size_t)(lane >> 5) * N * 32 + j;
    AGG_LOOP();

    float2 hs = __half22float2(Hp[(size_t)i * 32]);
    float sumx = ((s0.x + s1.x) + (s2.x + s3.x)) + hs.x;
    float sumy = ((s0.y + s1.y) + (s2.y + s3.y)) + hs.y;
    float dvi = dinv[i];
    const float* bb = (lane >= 32) ? bx : bz;
    float2 b = *(const float2*)(bb + 2 * j);
    float t0 = tanhf(fmaf(dvi, sumx, b.x));
    float t1 = tanhf(fmaf(dvi, sumy, b.y));
    float p0 = __shfl_xor(t0, 32, 64);
    float p1 = __shfl_xor(t1, 32, 64);
    float2 w = *(const float2*)(Wout + 2 * j);
    float prod = t0 * p0 * w.x + t1 * p1 * w.y;
    for (int o = 16; o >= 1; o >>= 1) prod += __shfl_xor(prod, o, 64);
    if (lane == 0) out[i] = prod + bout[0];
}

// ---------------------------------------------------------------------------

extern "C" void kernel_launch(void* const* d_in, const int* in_sizes, int n_in,
                              void* d_out, int out_size, void* d_ws, size_t ws_size,
                              hipStream_t stream) {
    const float* z = (const float*)d_in[0];
    const float* x = (const float*)d_in[1];
    const int* ei = (const int*)d_in[2];
    const float* We1 = (const float*)d_in[3];
    const float* be1 = (const float*)d_in[4];
    const float* We2 = (const float*)d_in[5];
    const float* be2 = (const float*)d_in[6];
    const float* Wf1 = (const float*)d_in[7];
    const float* bf1 = (const float*)d_in[8];
    const float* Wf2 = (const float*)d_in[9];
    const float* bf2 = (const float*)d_in[10];
    const float* Wout = (const float*)d_in[11];
    const float* bout = (const float*)d_in[12];
    float* out = (float*)d_out;

    int N = in_sizes[0] / 128;
    int E = in_sizes[2] / 2;
    const int* src = ei;
    const int* dst = ei + E;

    char* base = (char*)d_ws;
    size_t off = 0;
    auto take = [&](size_t nbytes) -> char* {
        char* p = base + off;
        off = (off + nbytes + 255) & ~(size_t)255;
        return p;
    };
    int NB = (N + 255) / 256;
    int* cnt = (int*)take((size_t)N * 4);
    int* bsum = (int*)take(1024 * 4);
    int* boff = (int*)take(1024 * 4);
    int* rowp = (int*)take(((size_t)N + 1) * 4);
    float* dinv = (float*)take((size_t)N * 4);
    int* dh = (int*)take(64 * 4);
    int* dp = (int*)take(64 * 4);
    int* doff = (int*)take(64 * 4);
    int* order = (int*)take((size_t)N * 4);
    int* rank = (int*)take((size_t)E * 4);
    int* csrc = (int*)take((size_t)E * 4);
    __half* Hh = (__half*)take((size_t)N * 64 * 2 * 2);  // 2 planes fp16
    __half* azh = (__half*)take((size_t)N * 64 * 2);
    __half* axh = (__half*)take((size_t)N * 64 * 2);

    int egrid = (E + 255) / 256;
    k_zero<<<NB, 256, 0, stream>>>(cnt, N, dh, dp);
    k_deg<<<egrid, 256, 0, stream>>>(dst, E, cnt, rank);
    k_scan1<<<NB, 256, 0, stream>>>(cnt, N, bsum);
    k_scan2<<<1, 256, 0, stream>>>(bsum, NB, boff, rowp, N, E);
    k_scan3<<<NB, 256, 0, stream>>>(cnt, boff, N, rowp, dinv, dh);
    k_fill<<<egrid, 256, 0, stream>>>(src, dst, rank, E, rowp, csrc);
    k_dscan<<<1, 64, 0, stream>>>(dh, doff);
    k_order<<<NB, 256, 0, stream>>>(cnt, doff, dp, order, N);

    dim3 mmgrid((N + 63) / 64, 2);
    int agrid = (N + 3) / 4;
    const __half2* H2 = (const __half2*)Hh;

    k_mm1<<<mmgrid, 256, 0, stream>>>(z, x, We1, Wf1, dinv, Hh, N);
    k_agg_act<<<agrid, 256, 0, stream>>>(order, rowp, csrc, dinv, H2, N, be1, bf1,
                                         azh, axh);
    k_mm2h<<<mmgrid, 256, 0, stream>>>(azh, axh, We2, Wf2, dinv, Hh, N);
    k_agg_final<<<agrid, 256, 0, stream>>>(order, rowp, csrc, dinv, H2, N, be2, bf2,
                                           Wout, bout, out);
}

// Round 9
// 329.195 us; speedup vs baseline: 1.3859x; 1.3859x over previous
//
#include <hip/hip_runtime.h>
#include <hip/hip_fp16.h>
#include <math.h>

#define RRELU_SLOPE 0.22916667f  // (1/8 + 1/3)/2 = 11/48

// ---------------------------------------------------------------------------
// CSR build: zero -> histogram(+rank) -> scan -> rank-based scatter.
// Plus degree-descending node order (counting sort) for agg load balance.
// ---------------------------------------------------------------------------

__global__ __launch_bounds__(256) void k_zero(int* __restrict__ cnt, int N,
                                              int* __restrict__ dh,
                                              int* __restrict__ dp) {
    int i = blockIdx.x * 256 + threadIdx.x;
    if (i < N) cnt[i] = 0;
    if (blockIdx.x == 0 && threadIdx.x < 64) {
        dh[threadIdx.x] = 0;
        dp[threadIdx.x] = 0;
    }
}

__global__ __launch_bounds__(256) void k_deg(const int* __restrict__ dst, int E,
                                             int* __restrict__ cnt,
                                             int* __restrict__ rank) {
    int e = blockIdx.x * 256 + threadIdx.x;
    if (e < E) rank[e] = atomicAdd(&cnt[dst[e]], 1);
}

__global__ __launch_bounds__(256) void k_scan1(const int* __restrict__ cnt, int N,
                                               int* __restrict__ bsum) {
    int i = blockIdx.x * 256 + threadIdx.x;
    int v = (i < N) ? cnt[i] : 0;
    for (int o = 32; o >= 1; o >>= 1) v += __shfl_xor(v, o, 64);
    __shared__ int ws[4];
    if ((threadIdx.x & 63) == 0) ws[threadIdx.x >> 6] = v;
    __syncthreads();
    if (threadIdx.x == 0) bsum[blockIdx.x] = ws[0] + ws[1] + ws[2] + ws[3];
}

__global__ __launch_bounds__(256) void k_scan2(const int* __restrict__ bsum, int NB,
                                               int* __restrict__ boff,
                                               int* __restrict__ rowp, int N, int E) {
    __shared__ int s[256];
    int t = threadIdx.x;
    int v[4];
    int loc = 0;
    for (int i = 0; i < 4; i++) {
        int idx = t * 4 + i;
        v[i] = (idx < NB) ? bsum[idx] : 0;
        loc += v[i];
    }
    s[t] = loc;
    __syncthreads();
    for (int o = 1; o < 256; o <<= 1) {
        int u = (t >= o) ? s[t - o] : 0;
        __syncthreads();
        s[t] += u;
        __syncthreads();
    }
    int excl = s[t] - loc;
    for (int i = 0; i < 4; i++) {
        int idx = t * 4 + i;
        if (idx < NB) { boff[idx] = excl; excl += v[i]; }
    }
    if (t == 0) rowp[N] = E;
}

// per-element exclusive scan + dinv + degree histogram (LDS pre-aggregated)
__global__ __launch_bounds__(256) void k_scan3(const int* __restrict__ cnt,
                                               const int* __restrict__ boff, int N,
                                               int* __restrict__ rowp,
                                               float* __restrict__ dinv,
                                               int* __restrict__ dh) {
    __shared__ int hist[64];
    if (threadIdx.x < 64) hist[threadIdx.x] = 0;
    int i = blockIdx.x * 256 + threadIdx.x;
    int lane = threadIdx.x & 63, wid = threadIdx.x >> 6;
    int v = (i < N) ? cnt[i] : 0;
    int inc = v;
    for (int o = 1; o < 64; o <<= 1) {
        int u = __shfl_up(inc, o, 64);
        if (lane >= o) inc += u;
    }
    __shared__ int wsum[4];
    if (lane == 63) wsum[wid] = inc;
    __syncthreads();
    int wo = 0;
    for (int w = 0; w < wid; w++) wo += wsum[w];
    if (i < N) {
        int excl = inc - v + wo + boff[blockIdx.x];
        rowp[i] = excl;
        dinv[i] = 1.0f / sqrtf((float)v + 1.0f);
        atomicAdd(&hist[min(v, 63)], 1);  // LDS atomic: cheap
    }
    __syncthreads();
    if (threadIdx.x < 64) {
        int h = hist[threadIdx.x];
        if (h) atomicAdd(&dh[threadIdx.x], h);  // <=64 global atomics/block
    }
}

// exclusive offsets for degree buckets, DESCENDING (bucket 63 first)
__global__ void k_dscan(const int* __restrict__ dh, int* __restrict__ doff) {
    int l = threadIdx.x;  // 0..63
    int v = dh[63 - l];
    int inc = v;
    for (int o = 1; o < 64; o <<= 1) {
        int u = __shfl_up(inc, o, 64);
        if (l >= o) inc += u;
    }
    doff[63 - l] = inc - v;
}

__global__ __launch_bounds__(256) void k_order(const int* __restrict__ cnt,
                                               const int* __restrict__ doff,
                                               int* __restrict__ dpos,
                                               int* __restrict__ order, int N) {
    int i = blockIdx.x * 256 + threadIdx.x;
    if (i >= N) return;
    int d = min(cnt[i], 63);
    int r = atomicAdd(&dpos[d], 1);
    order[doff[d] + r] = i;
}

__global__ __launch_bounds__(256) void k_fill(const int* __restrict__ src,
                                              const int* __restrict__ dst,
                                              const int* __restrict__ rank, int E,
                                              const int* __restrict__ rowp,
                                              int* __restrict__ csrc) {
    int e = blockIdx.x * 256 + threadIdx.x;
    if (e >= E) return;
    int d = dst[e];
    csrc[rowp[d] + rank[e]] = src[e];
}

// ---------------------------------------------------------------------------
// Layer-1 matmul (f32 A, K=128), one branch per block (blockIdx.y):
// Hh' = fp16(dinv[r] * (A @ W)). 64x64 tile, 4x4 register micro-kernel.
// ---------------------------------------------------------------------------
__global__ __launch_bounds__(256) void k_mm1(const float* __restrict__ A0,
                                             const float* __restrict__ A1,
                                             const float* __restrict__ W0,
                                             const float* __restrict__ W1,
                                             const float* __restrict__ dinv,
                                             __half* __restrict__ Hh, int N) {
    const float* A = blockIdx.y ? A1 : A0;
    const float* W = blockIdx.y ? W1 : W0;
    __half* H = Hh + (size_t)blockIdx.y * N * 64;

    __shared__ float As[64][20];
    __shared__ float Ws[16][64];

    const int tid = threadIdx.x;
    const int tc = tid & 15, tr = tid >> 4;
    const int row0 = blockIdx.x * 64;
    const int srow = tid >> 2, sk = (tid & 3) * 4;
    const int wk = tid >> 4, wc = (tid & 15) * 4;

    float acc[4][4] = {};

    for (int k0 = 0; k0 < 128; k0 += 16) {
        float4 av = make_float4(0.f, 0.f, 0.f, 0.f);
        int gr = row0 + srow;
        if (gr < N) av = *(const float4*)(A + (size_t)gr * 128 + k0 + sk);
        float4 wv = *(const float4*)(W + (size_t)(k0 + wk) * 64 + wc);
        __syncthreads();
        *(float4*)&As[srow][sk] = av;
        *(float4*)&Ws[wk][wc] = wv;
        __syncthreads();

#pragma unroll
        for (int k = 0; k < 16; k += 4) {
            float4 a4[4], w4[4];
#pragma unroll
            for (int i = 0; i < 4; i++) a4[i] = *(const float4*)&As[tr * 4 + i][k];
#pragma unroll
            for (int kk = 0; kk < 4; kk++) w4[kk] = *(const float4*)&Ws[k + kk][tc * 4];
#pragma unroll
            for (int i = 0; i < 4; i++) {
                const float* ap = (const float*)&a4[i];
#pragma unroll
                for (int kk = 0; kk < 4; kk++) {
                    const float* wp = (const float*)&w4[kk];
                    float a = ap[kk];
                    acc[i][0] = fmaf(a, wp[0], acc[i][0]);
                    acc[i][1] = fmaf(a, wp[1], acc[i][1]);
                    acc[i][2] = fmaf(a, wp[2], acc[i][2]);
                    acc[i][3] = fmaf(a, wp[3], acc[i][3]);
                }
            }
        }
    }

#pragma unroll
    for (int i = 0; i < 4; i++) {
        int r = row0 + tr * 4 + i;
        if (r < N) {
            float dv = dinv[r];
            union { __half2 h2[2]; uint2 u; } pk;
            pk.h2[0] = __floats2half2_rn(acc[i][0] * dv, acc[i][1] * dv);
            pk.h2[1] = __floats2half2_rn(acc[i][2] * dv, acc[i][3] * dv);
            *(uint2*)(H + (size_t)r * 64 + tc * 4) = pk.u;
        }
    }
}

// ---------------------------------------------------------------------------
// Layer-2 matmul: fp16 A planes (K=64), f32 W; fp16 output like k_mm1.
// ---------------------------------------------------------------------------
__global__ __launch_bounds__(256) void k_mm2h(const __half* __restrict__ A0,
                                              const __half* __restrict__ A1,
                                              const float* __restrict__ W0,
                                              const float* __restrict__ W1,
                                              const float* __restrict__ dinv,
                                              __half* __restrict__ Hh, int N) {
    const __half* A = blockIdx.y ? A1 : A0;
    const float* W = blockIdx.y ? W1 : W0;
    __half* H = Hh + (size_t)blockIdx.y * N * 64;

    __shared__ float As[64][20];
    __shared__ float Ws[16][64];

    const int tid = threadIdx.x;
    const int tc = tid & 15, tr = tid >> 4;
    const int row0 = blockIdx.x * 64;
    const int srow = tid >> 2, sk = (tid & 3) * 4;
    const int wk = tid >> 4, wc = (tid & 15) * 4;

    float acc[4][4] = {};

    for (int k0 = 0; k0 < 64; k0 += 16) {
        float4 av = make_float4(0.f, 0.f, 0.f, 0.f);
        int gr = row0 + srow;
        if (gr < N) {
            union { uint2 u; __half2 h2[2]; } cu;
            cu.u = *(const uint2*)(A + (size_t)gr * 64 + k0 + sk);
            float2 f01 = __half22float2(cu.h2[0]);
            float2 f23 = __half22float2(cu.h2[1]);
            av = make_float4(f01.x, f01.y, f23.x, f23.y);
        }
        float4 wv = *(const float4*)(W + (size_t)(k0 + wk) * 64 + wc);
        __syncthreads();
        *(float4*)&As[srow][sk] = av;
        *(float4*)&Ws[wk][wc] = wv;
        __syncthreads();

#pragma unroll
        for (int k = 0; k < 16; k += 4) {
            float4 a4[4], w4[4];
#pragma unroll
            for (int i = 0; i < 4; i++) a4[i] = *(const float4*)&As[tr * 4 + i][k];
#pragma unroll
            for (int kk = 0; kk < 4; kk++) w4[kk] = *(const float4*)&Ws[k + kk][tc * 4];
#pragma unroll
            for (int i = 0; i < 4; i++) {
                const float* ap = (const float*)&a4[i];
#pragma unroll
                for (int kk = 0; kk < 4; kk++) {
                    const float* wp = (const float*)&w4[kk];
                    float a = ap[kk];
                    acc[i][0] = fmaf(a, wp[0], acc[i][0]);
                    acc[i][1] = fmaf(a, wp[1], acc[i][1]);
                    acc[i][2] = fmaf(a, wp[2], acc[i][2]);
                    acc[i][3] = fmaf(a, wp[3], acc[i][3]);
                }
            }
        }
    }

#pragma unroll
    for (int i = 0; i < 4; i++) {
        int r = row0 + tr * 4 + i;
        if (r < N) {
            float dv = dinv[r];
            union { __half2 h2[2]; uint2 u; } pk;
            pk.h2[0] = __floats2half2_rn(acc[i][0] * dv, acc[i][1] * dv);
            pk.h2[1] = __floats2half2_rn(acc[i][2] * dv, acc[i][3] * dv);
            *(uint2*)(H + (size_t)r * 64 + tc * 4) = pk.u;
        }
    }
}

// ---------------------------------------------------------------------------
// Aggregation over pre-scaled fp16 planes, degree-sorted node order.
// 1 wave/node: lanes 0-31 = z plane, 32-63 = x plane. Pure gather+add,
// 8 edges in flight, 4 chains, f32 accumulation.
// ---------------------------------------------------------------------------
#define AGG_EDGE(S, C)                                   \
    {                                                    \
        float2 h_ = __half22float2(Hp[(size_t)(C) * 32]);\
        S.x += h_.x;                                     \
        S.y += h_.y;                                     \
    }

#define AGG_LOOP()                                                       \
    int beg = rowp[i], end = rowp[i + 1];                                \
    float2 s0 = {0.f, 0.f}, s1 = {0.f, 0.f}, s2 = {0.f, 0.f},            \
           s3 = {0.f, 0.f};                                              \
    int p = beg;                                                         \
    while (p < end && (p & 3)) { int c = csrc[p++]; AGG_EDGE(s0, c); }   \
    for (; p + 8 <= end; p += 8) {                                       \
        int4 ca = *(const int4*)(csrc + p);                              \
        int4 cb = *(const int4*)(csrc + p + 4);                          \
        AGG_EDGE(s0, ca.x); AGG_EDGE(s1, ca.y);                          \
        AGG_EDGE(s2, ca.z); AGG_EDGE(s3, ca.w);                          \
        AGG_EDGE(s0, cb.x); AGG_EDGE(s1, cb.y);                          \
        AGG_EDGE(s2, cb.z); AGG_EDGE(s3, cb.w);                          \
    }                                                                    \
    if (p + 4 <= end) {                                                  \
        int4 ca = *(const int4*)(csrc + p);                              \
        AGG_EDGE(s0, ca.x); AGG_EDGE(s1, ca.y);                          \
        AGG_EDGE(s2, ca.z); AGG_EDGE(s3, ca.w);                          \
        p += 4;                                                          \
    }                                                                    \
    while (p < end) { int c = csrc[p++]; AGG_EDGE(s0, c); }

__global__ __launch_bounds__(256) void k_agg_act(
    const int* __restrict__ order, const int* __restrict__ rowp,
    const int* __restrict__ csrc, const float* __restrict__ dinv,
    const __half2* __restrict__ H2, int N, const float* __restrict__ bz,
    const float* __restrict__ bx, __half* __restrict__ azh,
    __half* __restrict__ axh) {
    int wid = threadIdx.x >> 6, lane = threadIdx.x & 63;
    int idx = blockIdx.x * 4 + wid;
    if (idx >= N) return;
    int i = order[idx];
    int j = lane & 31;
    const __half2* Hp = H2 + (size_t)(lane >> 5) * N * 32 + j;
    AGG_LOOP();

    float2 hs = __half22float2(Hp[(size_t)i * 32]);
    float sumx = ((s0.x + s1.x) + (s2.x + s3.x)) + hs.x;
    float sumy = ((s0.y + s1.y) + (s2.y + s3.y)) + hs.y;
    float dvi = dinv[i];
    const float* bb = (lane >= 32) ? bx : bz;
    float2 b = *(const float2*)(bb + 2 * j);
    float f0 = fmaf(dvi, sumx, b.x);
    float f1 = fmaf(dvi, sumy, b.y);
    f0 = f0 >= 0.f ? f0 : f0 * RRELU_SLOPE;
    f1 = f1 >= 0.f ? f1 : f1 * RRELU_SLOPE;
    __half* ap = (lane >= 32) ? axh : azh;
    ((__half2*)ap)[(size_t)i * 32 + j] = __floats2half2_rn(f0, f1);
}

__global__ __launch_bounds__(256) void k_agg_final(
    const int* __restrict__ order, const int* __restrict__ rowp,
    const int* __restrict__ csrc, const float* __restrict__ dinv,
    const __half2* __restrict__ H2, int N, const float* __restrict__ bz,
    const float* __restrict__ bx, const float* __restrict__ Wout,
    const float* __restrict__ bout, float* __restrict__ out) {
    int wid = threadIdx.x >> 6, lane = threadIdx.x & 63;
    int idx = blockIdx.x * 4 + wid;
    if (idx >= N) return;
    int i = order[idx];
    int j = lane & 31;
    const __half2* Hp = H2 + (size_t)(lane >> 5) * N * 32 + j;
    AGG_LOOP();

    float2 hs = __half22float2(Hp[(size_t)i * 32]);
    float sumx = ((s0.x + s1.x) + (s2.x + s3.x)) + hs.x;
    float sumy = ((s0.y + s1.y) + (s2.y + s3.y)) + hs.y;
    float dvi = dinv[i];
    const float* bb = (lane >= 32) ? bx : bz;
    float2 b = *(const float2*)(bb + 2 * j);
    float t0 = tanhf(fmaf(dvi, sumx, b.x));
    float t1 = tanhf(fmaf(dvi, sumy, b.y));
    float p0 = __shfl_xor(t0, 32, 64);
    float p1 = __shfl_xor(t1, 32, 64);
    float2 w = *(const float2*)(Wout + 2 * j);
    float prod = t0 * p0 * w.x + t1 * p1 * w.y;
    for (int o = 16; o >= 1; o >>= 1) prod += __shfl_xor(prod, o, 64);
    if (lane == 0) out[i] = prod + bout[0];
}

// ---------------------------------------------------------------------------

extern "C" void kernel_launch(void* const* d_in, const int* in_sizes, int n_in,
                              void* d_out, int out_size, void* d_ws, size_t ws_size,
                              hipStream_t stream) {
    const float* z = (const float*)d_in[0];
    const float* x = (const float*)d_in[1];
    const int* ei = (const int*)d_in[2];
    const float* We1 = (const float*)d_in[3];
    const float* be1 = (const float*)d_in[4];
    const float* We2 = (const float*)d_in[5];
    const float* be2 = (const float*)d_in[6];
    const float* Wf1 = (const float*)d_in[7];
    const float* bf1 = (const float*)d_in[8];
    const float* Wf2 = (const float*)d_in[9];
    const float* bf2 = (const float*)d_in[10];
    const float* Wout = (const float*)d_in[11];
    const float* bout = (const float*)d_in[12];
    float* out = (float*)d_out;

    int N = in_sizes[0] / 128;
    int E = in_sizes[2] / 2;
    const int* src = ei;
    const int* dst = ei + E;

    char* base = (char*)d_ws;
    size_t off = 0;
    auto take = [&](size_t nbytes) -> char* {
        char* p = base + off;
        off = (off + nbytes + 255) & ~(size_t)255;
        return p;
    };
    int NB = (N + 255) / 256;
    int* cnt = (int*)take((size_t)N * 4);
    int* bsum = (int*)take(1024 * 4);
    int* boff = (int*)take(1024 * 4);
    int* rowp = (int*)take(((size_t)N + 1) * 4);
    float* dinv = (float*)take((size_t)N * 4);
    int* dh = (int*)take(64 * 4);
    int* dp = (int*)take(64 * 4);
    int* doff = (int*)take(64 * 4);
    int* order = (int*)take((size_t)N * 4);
    int* rank = (int*)take((size_t)E * 4);
    int* csrc = (int*)take((size_t)E * 4);
    __half* Hh = (__half*)take((size_t)N * 64 * 2 * 2);  // 2 planes fp16
    __half* azh = (__half*)take((size_t)N * 64 * 2);
    __half* axh = (__half*)take((size_t)N * 64 * 2);

    int egrid = (E + 255) / 256;
    k_zero<<<NB, 256, 0, stream>>>(cnt, N, dh, dp);
    k_deg<<<egrid, 256, 0, stream>>>(dst, E, cnt, rank);
    k_scan1<<<NB, 256, 0, stream>>>(cnt, N, bsum);
    k_scan2<<<1, 256, 0, stream>>>(bsum, NB, boff, rowp, N, E);
    k_scan3<<<NB, 256, 0, stream>>>(cnt, boff, N, rowp, dinv, dh);
    k_fill<<<egrid, 256, 0, stream>>>(src, dst, rank, E, rowp, csrc);
    k_dscan<<<1, 64, 0, stream>>>(dh, doff);
    k_order<<<NB, 256, 0, stream>>>(cnt, doff, dp, order, N);

    dim3 mmgrid((N + 63) / 64, 2);
    int agrid = (N + 3) / 4;
    const __half2* H2 = (const __half2*)Hh;

    k_mm1<<<mmgrid, 256, 0, stream>>>(z, x, We1, Wf1, dinv, Hh, N);
    k_agg_act<<<agrid, 256, 0, stream>>>(order, rowp, csrc, dinv, H2, N, be1, bf1,
                                         azh, axh);
    k_mm2h<<<mmgrid, 256, 0, stream>>>(azh, axh, We2, Wf2, dinv, Hh, N);
    k_agg_final<<<agrid, 256, 0, stream>>>(order, rowp, csrc, dinv, H2, N, be2, bf2,
                                           Wout, bout, out);
}

// Round 10
// 203.305 us; speedup vs baseline: 2.2441x; 1.6192x over previous
//
#include <hip/hip_runtime.h>
#include <hip/hip_fp16.h>
#include <math.h>

#define RRELU_SLOPE 0.22916667f  // (1/8 + 1/3)/2 = 11/48

// ---------------------------------------------------------------------------
// CSR build: zero -> histogram(+rank) -> scan -> rank-based scatter.
// Plus degree-descending node order (counting sort) for agg load balance.
// ---------------------------------------------------------------------------

__global__ __launch_bounds__(256) void k_zero(int* __restrict__ cnt, int N,
                                              int* __restrict__ dh,
                                              int* __restrict__ dp) {
    int i = blockIdx.x * 256 + threadIdx.x;
    if (i < N) cnt[i] = 0;
    if (blockIdx.x == 0 && threadIdx.x < 64) {
        dh[threadIdx.x] = 0;
        dp[threadIdx.x] = 0;
    }
}

__global__ __launch_bounds__(256) void k_deg(const int* __restrict__ dst, int E,
                                             int* __restrict__ cnt,
                                             int* __restrict__ rank) {
    int e = blockIdx.x * 256 + threadIdx.x;
    if (e < E) rank[e] = atomicAdd(&cnt[dst[e]], 1);
}

__global__ __launch_bounds__(256) void k_scan1(const int* __restrict__ cnt, int N,
                                               int* __restrict__ bsum) {
    int i = blockIdx.x * 256 + threadIdx.x;
    int v = (i < N) ? cnt[i] : 0;
    for (int o = 32; o >= 1; o >>= 1) v += __shfl_xor(v, o, 64);
    __shared__ int ws[4];
    if ((threadIdx.x & 63) == 0) ws[threadIdx.x >> 6] = v;
    __syncthreads();
    if (threadIdx.x == 0) bsum[blockIdx.x] = ws[0] + ws[1] + ws[2] + ws[3];
}

__global__ __launch_bounds__(256) void k_scan2(const int* __restrict__ bsum, int NB,
                                               int* __restrict__ boff,
                                               int* __restrict__ rowp, int N, int E) {
    __shared__ int s[256];
    int t = threadIdx.x;
    int v[4];
    int loc = 0;
    for (int i = 0; i < 4; i++) {
        int idx = t * 4 + i;
        v[i] = (idx < NB) ? bsum[idx] : 0;
        loc += v[i];
    }
    s[t] = loc;
    __syncthreads();
    for (int o = 1; o < 256; o <<= 1) {
        int u = (t >= o) ? s[t - o] : 0;
        __syncthreads();
        s[t] += u;
        __syncthreads();
    }
    int excl = s[t] - loc;
    for (int i = 0; i < 4; i++) {
        int idx = t * 4 + i;
        if (idx < NB) { boff[idx] = excl; excl += v[i]; }
    }
    if (t == 0) rowp[N] = E;
}

// per-element exclusive scan + dinv + degree histogram (LDS pre-aggregated)
__global__ __launch_bounds__(256) void k_scan3(const int* __restrict__ cnt,
                                               const int* __restrict__ boff, int N,
                                               int* __restrict__ rowp,
                                               float* __restrict__ dinv,
                                               int* __restrict__ dh) {
    __shared__ int hist[64];
    if (threadIdx.x < 64) hist[threadIdx.x] = 0;
    int i = blockIdx.x * 256 + threadIdx.x;
    int lane = threadIdx.x & 63, wid = threadIdx.x >> 6;
    int v = (i < N) ? cnt[i] : 0;
    int inc = v;
    for (int o = 1; o < 64; o <<= 1) {
        int u = __shfl_up(inc, o, 64);
        if (lane >= o) inc += u;
    }
    __shared__ int wsum[4];
    if (lane == 63) wsum[wid] = inc;
    __syncthreads();
    int wo = 0;
    for (int w = 0; w < wid; w++) wo += wsum[w];
    if (i < N) {
        int excl = inc - v + wo + boff[blockIdx.x];
        rowp[i] = excl;
        dinv[i] = 1.0f / sqrtf((float)v + 1.0f);
        atomicAdd(&hist[min(v, 63)], 1);  // LDS atomic: cheap
    }
    __syncthreads();
    if (threadIdx.x < 64) {
        int h = hist[threadIdx.x];
        if (h) atomicAdd(&dh[threadIdx.x], h);  // <=64 global atomics/block
    }
}

// exclusive offsets for degree buckets, DESCENDING (bucket 63 first)
__global__ void k_dscan(const int* __restrict__ dh, int* __restrict__ doff) {
    int l = threadIdx.x;  // 0..63
    int v = dh[63 - l];
    int inc = v;
    for (int o = 1; o < 64; o <<= 1) {
        int u = __shfl_up(inc, o, 64);
        if (l >= o) inc += u;
    }
    doff[63 - l] = inc - v;
}

// counting-sort scatter with LDS pre-aggregation: per-block bucket counts in
// LDS (thread rank via LDS atomic), one global atomicAdd per bucket per block.
__global__ __launch_bounds__(256) void k_order(const int* __restrict__ cnt,
                                               const int* __restrict__ doff,
                                               int* __restrict__ dpos,
                                               int* __restrict__ order, int N) {
    __shared__ int hist[64];
    __shared__ int base[64];
    if (threadIdx.x < 64) hist[threadIdx.x] = 0;
    __syncthreads();
    int i = blockIdx.x * 256 + threadIdx.x;
    int d = 0, r = 0;
    bool valid = (i < N);
    if (valid) {
        d = min(cnt[i], 63);
        r = atomicAdd(&hist[d], 1);  // LDS atomic
    }
    __syncthreads();
    if (threadIdx.x < 64) {
        int h = hist[threadIdx.x];
        base[threadIdx.x] = h ? atomicAdd(&dpos[threadIdx.x], h) : 0;
    }
    __syncthreads();
    if (valid) order[doff[d] + base[d] + r] = i;
}

__global__ __launch_bounds__(256) void k_fill(const int* __restrict__ src,
                                              const int* __restrict__ dst,
                                              const int* __restrict__ rank, int E,
                                              const int* __restrict__ rowp,
                                              int* __restrict__ csrc) {
    int e = blockIdx.x * 256 + threadIdx.x;
    if (e >= E) return;
    int d = dst[e];
    csrc[rowp[d] + rank[e]] = src[e];
}

// ---------------------------------------------------------------------------
// Layer-1 matmul (f32 A, K=128), one branch per block (blockIdx.y):
// Hh' = fp16(dinv[r] * (A @ W)). 64x64 tile, 4x4 register micro-kernel.
// ---------------------------------------------------------------------------
__global__ __launch_bounds__(256) void k_mm1(const float* __restrict__ A0,
                                             const float* __restrict__ A1,
                                             const float* __restrict__ W0,
                                             const float* __restrict__ W1,
                                             const float* __restrict__ dinv,
                                             __half* __restrict__ Hh, int N) {
    const float* A = blockIdx.y ? A1 : A0;
    const float* W = blockIdx.y ? W1 : W0;
    __half* H = Hh + (size_t)blockIdx.y * N * 64;

    __shared__ float As[64][20];
    __shared__ float Ws[16][64];

    const int tid = threadIdx.x;
    const int tc = tid & 15, tr = tid >> 4;
    const int row0 = blockIdx.x * 64;
    const int srow = tid >> 2, sk = (tid & 3) * 4;
    const int wk = tid >> 4, wc = (tid & 15) * 4;

    float acc[4][4] = {};

    for (int k0 = 0; k0 < 128; k0 += 16) {
        float4 av = make_float4(0.f, 0.f, 0.f, 0.f);
        int gr = row0 + srow;
        if (gr < N) av = *(const float4*)(A + (size_t)gr * 128 + k0 + sk);
        float4 wv = *(const float4*)(W + (size_t)(k0 + wk) * 64 + wc);
        __syncthreads();
        *(float4*)&As[srow][sk] = av;
        *(float4*)&Ws[wk][wc] = wv;
        __syncthreads();

#pragma unroll
        for (int k = 0; k < 16; k += 4) {
            float4 a4[4], w4[4];
#pragma unroll
            for (int i = 0; i < 4; i++) a4[i] = *(const float4*)&As[tr * 4 + i][k];
#pragma unroll
            for (int kk = 0; kk < 4; kk++) w4[kk] = *(const float4*)&Ws[k + kk][tc * 4];
#pragma unroll
            for (int i = 0; i < 4; i++) {
                const float* ap = (const float*)&a4[i];
#pragma unroll
                for (int kk = 0; kk < 4; kk++) {
                    const float* wp = (const float*)&w4[kk];
                    float a = ap[kk];
                    acc[i][0] = fmaf(a, wp[0], acc[i][0]);
                    acc[i][1] = fmaf(a, wp[1], acc[i][1]);
                    acc[i][2] = fmaf(a, wp[2], acc[i][2]);
                    acc[i][3] = fmaf(a, wp[3], acc[i][3]);
                }
            }
        }
    }

#pragma unroll
    for (int i = 0; i < 4; i++) {
        int r = row0 + tr * 4 + i;
        if (r < N) {
            float dv = dinv[r];
            union { __half2 h2[2]; uint2 u; } pk;
            pk.h2[0] = __floats2half2_rn(acc[i][0] * dv, acc[i][1] * dv);
            pk.h2[1] = __floats2half2_rn(acc[i][2] * dv, acc[i][3] * dv);
            *(uint2*)(H + (size_t)r * 64 + tc * 4) = pk.u;
        }
    }
}

// ---------------------------------------------------------------------------
// Layer-2 matmul: fp16 A planes (K=64), f32 W; fp16 output like k_mm1.
// ---------------------------------------------------------------------------
__global__ __launch_bounds__(256) void k_mm2h(const __half* __restrict__ A0,
                                              const __half* __restrict__ A1,
                                              const float* __restrict__ W0,
                                              const float* __restrict__ W1,
                                              const float* __restrict__ dinv,
                                              __half* __restrict__ Hh, int N) {
    const __half* A = blockIdx.y ? A1 : A0;
    const float* W = blockIdx.y ? W1 : W0;
    __half* H = Hh + (size_t)blockIdx.y * N * 64;

    __shared__ float As[64][20];
    __shared__ float Ws[16][64];

    const int tid = threadIdx.x;
    const int tc = tid & 15, tr = tid >> 4;
    const int row0 = blockIdx.x * 64;
    const int srow = tid >> 2, sk = (tid & 3) * 4;
    const int wk = tid >> 4, wc = (tid & 15) * 4;

    float acc[4][4] = {};

    for (int k0 = 0; k0 < 64; k0 += 16) {
        float4 av = make_float4(0.f, 0.f, 0.f, 0.f);
        int gr = row0 + srow;
        if (gr < N) {
            union { uint2 u; __half2 h2[2]; } cu;
            cu.u = *(const uint2*)(A + (size_t)gr * 64 + k0 + sk);
            float2 f01 = __half22float2(cu.h2[0]);
            float2 f23 = __half22float2(cu.h2[1]);
            av = make_float4(f01.x, f01.y, f23.x, f23.y);
        }
        float4 wv = *(const float4*)(W + (size_t)(k0 + wk) * 64 + wc);
        __syncthreads();
        *(float4*)&As[srow][sk] = av;
        *(float4*)&Ws[wk][wc] = wv;
        __syncthreads();

#pragma unroll
        for (int k = 0; k < 16; k += 4) {
            float4 a4[4], w4[4];
#pragma unroll
            for (int i = 0; i < 4; i++) a4[i] = *(const float4*)&As[tr * 4 + i][k];
#pragma unroll
            for (int kk = 0; kk < 4; kk++) w4[kk] = *(const float4*)&Ws[k + kk][tc * 4];
#pragma unroll
            for (int i = 0; i < 4; i++) {
                const float* ap = (const float*)&a4[i];
#pragma unroll
                for (int kk = 0; kk < 4; kk++) {
                    const float* wp = (const float*)&w4[kk];
                    float a = ap[kk];
                    acc[i][0] = fmaf(a, wp[0], acc[i][0]);
                    acc[i][1] = fmaf(a, wp[1], acc[i][1]);
                    acc[i][2] = fmaf(a, wp[2], acc[i][2]);
                    acc[i][3] = fmaf(a, wp[3], acc[i][3]);
                }
            }
        }
    }

#pragma unroll
    for (int i = 0; i < 4; i++) {
        int r = row0 + tr * 4 + i;
        if (r < N) {
            float dv = dinv[r];
            union { __half2 h2[2]; uint2 u; } pk;
            pk.h2[0] = __floats2half2_rn(acc[i][0] * dv, acc[i][1] * dv);
            pk.h2[1] = __floats2half2_rn(acc[i][2] * dv, acc[i][3] * dv);
            *(uint2*)(H + (size_t)r * 64 + tc * 4) = pk.u;
        }
    }
}

// ---------------------------------------------------------------------------
// Aggregation over pre-scaled fp16 planes, degree-sorted node order.
// 1 wave/node: lanes 0-31 = z plane, 32-63 = x plane. Pure gather+add,
// 8 edges in flight, 4 chains, f32 accumulation.
// ---------------------------------------------------------------------------
#define AGG_EDGE(S, C)                                   \
    {                                                    \
        float2 h_ = __half22float2(Hp[(size_t)(C) * 32]);\
        S.x += h_.x;                                     \
        S.y += h_.y;                                     \
    }

#define AGG_LOOP()                                                       \
    int beg = rowp[i], end = rowp[i + 1];                                \
    float2 s0 = {0.f, 0.f}, s1 = {0.f, 0.f}, s2 = {0.f, 0.f},            \
           s3 = {0.f, 0.f};                                              \
    int p = beg;                                                         \
    while (p < end && (p & 3)) { int c = csrc[p++]; AGG_EDGE(s0, c); }   \
    for (; p + 8 <= end; p += 8) {                                       \
        int4 ca = *(const int4*)(csrc + p);                              \
        int4 cb = *(const int4*)(csrc + p + 4);                          \
        AGG_EDGE(s0, ca.x); AGG_EDGE(s1, ca.y);                          \
        AGG_EDGE(s2, ca.z); AGG_EDGE(s3, ca.w);                          \
        AGG_EDGE(s0, cb.x); AGG_EDGE(s1, cb.y);                          \
        AGG_EDGE(s2, cb.z); AGG_EDGE(s3, cb.w);                          \
    }                                                                    \
    if (p + 4 <= end) {                                                  \
        int4 ca = *(const int4*)(csrc + p);                              \
        AGG_EDGE(s0, ca.x); AGG_EDGE(s1, ca.y);                          \
        AGG_EDGE(s2, ca.z); AGG_EDGE(s3, ca.w);                          \
        p += 4;                                                          \
    }                                                                    \
    while (p < end) { int c = csrc[p++]; AGG_EDGE(s0, c); }

__global__ __launch_bounds__(256) void k_agg_act(
    const int* __restrict__ order, const int* __restrict__ rowp,
    const int* __restrict__ csrc, const float* __restrict__ dinv,
    const __half2* __restrict__ H2, int N, const float* __restrict__ bz,
    const float* __restrict__ bx, __half* __restrict__ azh,
    __half* __restrict__ axh) {
    int wid = threadIdx.x >> 6, lane = threadIdx.x & 63;
    int idx = blockIdx.x * 4 + wid;
    if (idx >= N) return;
    int i = order[idx];
    int j = lane & 31;
    const __half2* Hp = H2 + (size_t)(lane >> 5) * N * 32 + j;
    AGG_LOOP();

    float2 hs = __half22float2(Hp[(size_t)i * 32]);
    float sumx = ((s0.x + s1.x) + (s2.x + s3.x)) + hs.x;
    float sumy = ((s0.y + s1.y) + (s2.y + s3.y)) + hs.y;
    float dvi = dinv[i];
    const float* bb = (lane >= 32) ? bx : bz;
    float2 b = *(const float2*)(bb + 2 * j);
    float f0 = fmaf(dvi, sumx, b.x);
    float f1 = fmaf(dvi, sumy, b.y);
    f0 = f0 >= 0.f ? f0 : f0 * RRELU_SLOPE;
    f1 = f1 >= 0.f ? f1 : f1 * RRELU_SLOPE;
    __half* ap = (lane >= 32) ? axh : azh;
    ((__half2*)ap)[(size_t)i * 32 + j] = __floats2half2_rn(f0, f1);
}

__global__ __launch_bounds__(256) void k_agg_final(
    const int* __restrict__ order, const int* __restrict__ rowp,
    const int* __restrict__ csrc, const float* __restrict__ dinv,
    const __half2* __restrict__ H2, int N, const float* __restrict__ bz,
    const float* __restrict__ bx, const float* __restrict__ Wout,
    const float* __restrict__ bout, float* __restrict__ out) {
    int wid = threadIdx.x >> 6, lane = threadIdx.x & 63;
    int idx = blockIdx.x * 4 + wid;
    if (idx >= N) return;
    int i = order[idx];
    int j = lane & 31;
    const __half2* Hp = H2 + (size_t)(lane >> 5) * N * 32 + j;
    AGG_LOOP();

    float2 hs = __half22float2(Hp[(size_t)i * 32]);
    float sumx = ((s0.x + s1.x) + (s2.x + s3.x)) + hs.x;
    float sumy = ((s0.y + s1.y) + (s2.y + s3.y)) + hs.y;
    float dvi = dinv[i];
    const float* bb = (lane >= 32) ? bx : bz;
    float2 b = *(const float2*)(bb + 2 * j);
    float t0 = tanhf(fmaf(dvi, sumx, b.x));
    float t1 = tanhf(fmaf(dvi, sumy, b.y));
    float p0 = __shfl_xor(t0, 32, 64);
    float p1 = __shfl_xor(t1, 32, 64);
    float2 w = *(const float2*)(Wout + 2 * j);
    float prod = t0 * p0 * w.x + t1 * p1 * w.y;
    for (int o = 16; o >= 1; o >>= 1) prod += __shfl_xor(prod, o, 64);
    if (lane == 0) out[i] = prod + bout[0];
}

// ---------------------------------------------------------------------------

extern "C" void kernel_launch(void* const* d_in, const int* in_sizes, int n_in,
                              void* d_out, int out_size, void* d_ws, size_t ws_size,
                              hipStream_t stream) {
    const float* z = (const float*)d_in[0];
    const float* x = (const float*)d_in[1];
    const int* ei = (const int*)d_in[2];
    const float* We1 = (const float*)d_in[3];
    const float* be1 = (const float*)d_in[4];
    const float* We2 = (const float*)d_in[5];
    const float* be2 = (const float*)d_in[6];
    const float* Wf1 = (const float*)d_in[7];
    const float* bf1 = (const float*)d_in[8];
    const float* Wf2 = (const float*)d_in[9];
    const float* bf2 = (const float*)d_in[10];
    const float* Wout = (const float*)d_in[11];
    const float* bout = (const float*)d_in[12];
    float* out = (float*)d_out;

    int N = in_sizes[0] / 128;
    int E = in_sizes[2] / 2;
    const int* src = ei;
    const int* dst = ei + E;

    char* base = (char*)d_ws;
    size_t off = 0;
    auto take = [&](size_t nbytes) -> char* {
        char* p = base + off;
        off = (off + nbytes + 255) & ~(size_t)255;
        return p;
    };
    int NB = (N + 255) / 256;
    int* cnt = (int*)take((size_t)N * 4);
    int* bsum = (int*)take(1024 * 4);
    int* boff = (int*)take(1024 * 4);
    int* rowp = (int*)take(((size_t)N + 1) * 4);
    float* dinv = (float*)take((size_t)N * 4);
    int* dh = (int*)take(64 * 4);
    int* dp = (int*)take(64 * 4);
    int* doff = (int*)take(64 * 4);
    int* order = (int*)take((size_t)N * 4);
    int* rank = (int*)take((size_t)E * 4);
    int* csrc = (int*)take((size_t)E * 4);
    __half* Hh = (__half*)take((size_t)N * 64 * 2 * 2);  // 2 planes fp16
    __half* azh = (__half*)take((size_t)N * 64 * 2);
    __half* axh = (__half*)take((size_t)N * 64 * 2);

    int egrid = (E + 255) / 256;
    k_zero<<<NB, 256, 0, stream>>>(cnt, N, dh, dp);
    k_deg<<<egrid, 256, 0, stream>>>(dst, E, cnt, rank);
    k_scan1<<<NB, 256, 0, stream>>>(cnt, N, bsum);
    k_scan2<<<1, 256, 0, stream>>>(bsum, NB, boff, rowp, N, E);
    k_scan3<<<NB, 256, 0, stream>>>(cnt, boff, N, rowp, dinv, dh);
    k_fill<<<egrid, 256, 0, stream>>>(src, dst, rank, E, rowp, csrc);
    k_dscan<<<1, 64, 0, stream>>>(dh, doff);
    k_order<<<NB, 256, 0, stream>>>(cnt, doff, dp, order, N);

    dim3 mmgrid((N + 63) / 64, 2);
    int agrid = (N + 3) / 4;
    const __half2* H2 = (const __half2*)Hh;

    k_mm1<<<mmgrid, 256, 0, stream>>>(z, x, We1, Wf1, dinv, Hh, N);
    k_agg_act<<<agrid, 256, 0, stream>>>(order, rowp, csrc, dinv, H2, N, be1, bf1,
                                         azh, axh);
    k_mm2h<<<mmgrid, 256, 0, stream>>>(azh, axh, We2, Wf2, dinv, Hh, N);
    k_agg_final<<<agrid, 256, 0, stream>>>(order, rowp, csrc, dinv, H2, N, be2, bf2,
                                           Wout, bout, out);
}

// Round 11
// 195.270 us; speedup vs baseline: 2.3364x; 1.0411x over previous
//
#include <hip/hip_runtime.h>
#include <hip/hip_fp16.h>
#include <math.h>

#define RRELU_SLOPE 0.22916667f  // (1/8 + 1/3)/2 = 11/48

// ---------------------------------------------------------------------------
// CSR build: zero -> histogram(+rank) -> scan -> rank-based scatter
// ---------------------------------------------------------------------------

__global__ __launch_bounds__(256) void k_zero(int* __restrict__ cnt, int N) {
    int i = blockIdx.x * 256 + threadIdx.x;
    if (i < N) cnt[i] = 0;
}

__global__ __launch_bounds__(256) void k_deg(const int* __restrict__ dst, int E,
                                             int* __restrict__ cnt,
                                             int* __restrict__ rank) {
    int e = blockIdx.x * 256 + threadIdx.x;
    if (e < E) rank[e] = atomicAdd(&cnt[dst[e]], 1);
}

__global__ __launch_bounds__(256) void k_scan1(const int* __restrict__ cnt, int N,
                                               int* __restrict__ bsum) {
    int i = blockIdx.x * 256 + threadIdx.x;
    int v = (i < N) ? cnt[i] : 0;
    for (int o = 32; o >= 1; o >>= 1) v += __shfl_xor(v, o, 64);
    __shared__ int ws[4];
    if ((threadIdx.x & 63) == 0) ws[threadIdx.x >> 6] = v;
    __syncthreads();
    if (threadIdx.x == 0) bsum[blockIdx.x] = ws[0] + ws[1] + ws[2] + ws[3];
}

__global__ __launch_bounds__(256) void k_scan2(const int* __restrict__ bsum, int NB,
                                               int* __restrict__ boff,
                                               int* __restrict__ rowp, int N, int E) {
    __shared__ int s[256];
    int t = threadIdx.x;
    int v[4];
    int loc = 0;
    for (int i = 0; i < 4; i++) {
        int idx = t * 4 + i;
        v[i] = (idx < NB) ? bsum[idx] : 0;
        loc += v[i];
    }
    s[t] = loc;
    __syncthreads();
    for (int o = 1; o < 256; o <<= 1) {
        int u = (t >= o) ? s[t - o] : 0;
        __syncthreads();
        s[t] += u;
        __syncthreads();
    }
    int excl = s[t] - loc;
    for (int i = 0; i < 4; i++) {
        int idx = t * 4 + i;
        if (idx < NB) { boff[idx] = excl; excl += v[i]; }
    }
    if (t == 0) rowp[N] = E;
}

__global__ __launch_bounds__(256) void k_scan3(const int* __restrict__ cnt,
                                               const int* __restrict__ boff, int N,
                                               int* __restrict__ rowp,
                                               float* __restrict__ dinv) {
    int i = blockIdx.x * 256 + threadIdx.x;
    int lane = threadIdx.x & 63, wid = threadIdx.x >> 6;
    int v = (i < N) ? cnt[i] : 0;
    int inc = v;
    for (int o = 1; o < 64; o <<= 1) {
        int u = __shfl_up(inc, o, 64);
        if (lane >= o) inc += u;
    }
    __shared__ int wsum[4];
    if (lane == 63) wsum[wid] = inc;
    __syncthreads();
    int wo = 0;
    for (int w = 0; w < wid; w++) wo += wsum[w];
    if (i < N) {
        int excl = inc - v + wo + boff[blockIdx.x];
        rowp[i] = excl;
        dinv[i] = 1.0f / sqrtf((float)v + 1.0f);
    }
}

__global__ __launch_bounds__(256) void k_fill(const int* __restrict__ src,
                                              const int* __restrict__ dst,
                                              const int* __restrict__ rank, int E,
                                              const int* __restrict__ rowp,
                                              int* __restrict__ csrc) {
    int e = blockIdx.x * 256 + threadIdx.x;
    if (e >= E) return;
    int d = dst[e];
    csrc[rowp[d] + rank[e]] = src[e];
}

// ---------------------------------------------------------------------------
// Layer-1 matmul (f32 A, K=128), one branch per block (blockIdx.y):
// Hh' = fp16(dinv[r] * (A @ W)). 64x64 tile, 4x4 register micro-kernel.
// ---------------------------------------------------------------------------
__global__ __launch_bounds__(256) void k_mm1(const float* __restrict__ A0,
                                             const float* __restrict__ A1,
                                             const float* __restrict__ W0,
                                             const float* __restrict__ W1,
                                             const float* __restrict__ dinv,
                                             __half* __restrict__ Hh, int N) {
    const float* A = blockIdx.y ? A1 : A0;
    const float* W = blockIdx.y ? W1 : W0;
    __half* H = Hh + (size_t)blockIdx.y * N * 64;

    __shared__ float As[64][20];
    __shared__ float Ws[16][64];

    const int tid = threadIdx.x;
    const int tc = tid & 15, tr = tid >> 4;
    const int row0 = blockIdx.x * 64;
    const int srow = tid >> 2, sk = (tid & 3) * 4;
    const int wk = tid >> 4, wc = (tid & 15) * 4;

    float acc[4][4] = {};

    for (int k0 = 0; k0 < 128; k0 += 16) {
        float4 av = make_float4(0.f, 0.f, 0.f, 0.f);
        int gr = row0 + srow;
        if (gr < N) av = *(const float4*)(A + (size_t)gr * 128 + k0 + sk);
        float4 wv = *(const float4*)(W + (size_t)(k0 + wk) * 64 + wc);
        __syncthreads();
        *(float4*)&As[srow][sk] = av;
        *(float4*)&Ws[wk][wc] = wv;
        __syncthreads();

#pragma unroll
        for (int k = 0; k < 16; k += 4) {
            float4 a4[4], w4[4];
#pragma unroll
            for (int i = 0; i < 4; i++) a4[i] = *(const float4*)&As[tr * 4 + i][k];
#pragma unroll
            for (int kk = 0; kk < 4; kk++) w4[kk] = *(const float4*)&Ws[k + kk][tc * 4];
#pragma unroll
            for (int i = 0; i < 4; i++) {
                const float* ap = (const float*)&a4[i];
#pragma unroll
                for (int kk = 0; kk < 4; kk++) {
                    const float* wp = (const float*)&w4[kk];
                    float a = ap[kk];
                    acc[i][0] = fmaf(a, wp[0], acc[i][0]);
                    acc[i][1] = fmaf(a, wp[1], acc[i][1]);
                    acc[i][2] = fmaf(a, wp[2], acc[i][2]);
                    acc[i][3] = fmaf(a, wp[3], acc[i][3]);
                }
            }
        }
    }

#pragma unroll
    for (int i = 0; i < 4; i++) {
        int r = row0 + tr * 4 + i;
        if (r < N) {
            float dv = dinv[r];
            union { __half2 h2[2]; uint2 u; } pk;
            pk.h2[0] = __floats2half2_rn(acc[i][0] * dv, acc[i][1] * dv);
            pk.h2[1] = __floats2half2_rn(acc[i][2] * dv, acc[i][3] * dv);
            *(uint2*)(H + (size_t)r * 64 + tc * 4) = pk.u;
        }
    }
}

// ---------------------------------------------------------------------------
// Layer-2 matmul: fp16 A planes (K=64), f32 W; fp16 output like k_mm1.
// ---------------------------------------------------------------------------
__global__ __launch_bounds__(256) void k_mm2h(const __half* __restrict__ A0,
                                              const __half* __restrict__ A1,
                                              const float* __restrict__ W0,
                                              const float* __restrict__ W1,
                                              const float* __restrict__ dinv,
                                              __half* __restrict__ Hh, int N) {
    const __half* A = blockIdx.y ? A1 : A0;
    const float* W = blockIdx.y ? W1 : W0;
    __half* H = Hh + (size_t)blockIdx.y * N * 64;

    __shared__ float As[64][20];
    __shared__ float Ws[16][64];

    const int tid = threadIdx.x;
    const int tc = tid & 15, tr = tid >> 4;
    const int row0 = blockIdx.x * 64;
    const int srow = tid >> 2, sk = (tid & 3) * 4;
    const int wk = tid >> 4, wc = (tid & 15) * 4;

    float acc[4][4] = {};

    for (int k0 = 0; k0 < 64; k0 += 16) {
        float4 av = make_float4(0.f, 0.f, 0.f, 0.f);
        int gr = row0 + srow;
        if (gr < N) {
            union { uint2 u; __half2 h2[2]; } cu;
            cu.u = *(const uint2*)(A + (size_t)gr * 64 + k0 + sk);
            float2 f01 = __half22float2(cu.h2[0]);
            float2 f23 = __half22float2(cu.h2[1]);
            av = make_float4(f01.x, f01.y, f23.x, f23.y);
        }
        float4 wv = *(const float4*)(W + (size_t)(k0 + wk) * 64 + wc);
        __syncthreads();
        *(float4*)&As[srow][sk] = av;
        *(float4*)&Ws[wk][wc] = wv;
        __syncthreads();

#pragma unroll
        for (int k = 0; k < 16; k += 4) {
            float4 a4[4], w4[4];
#pragma unroll
            for (int i = 0; i < 4; i++) a4[i] = *(const float4*)&As[tr * 4 + i][k];
#pragma unroll
            for (int kk = 0; kk < 4; kk++) w4[kk] = *(const float4*)&Ws[k + kk][tc * 4];
#pragma unroll
            for (int i = 0; i < 4; i++) {
                const float* ap = (const float*)&a4[i];
#pragma unroll
                for (int kk = 0; kk < 4; kk++) {
                    const float* wp = (const float*)&w4[kk];
                    float a = ap[kk];
                    acc[i][0] = fmaf(a, wp[0], acc[i][0]);
                    acc[i][1] = fmaf(a, wp[1], acc[i][1]);
                    acc[i][2] = fmaf(a, wp[2], acc[i][2]);
                    acc[i][3] = fmaf(a, wp[3], acc[i][3]);
                }
            }
        }
    }

#pragma unroll
    for (int i = 0; i < 4; i++) {
        int r = row0 + tr * 4 + i;
        if (r < N) {
            float dv = dinv[r];
            union { __half2 h2[2]; uint2 u; } pk;
            pk.h2[0] = __floats2half2_rn(acc[i][0] * dv, acc[i][1] * dv);
            pk.h2[1] = __floats2half2_rn(acc[i][2] * dv, acc[i][3] * dv);
            *(uint2*)(H + (size_t)r * 64 + tc * 4) = pk.u;
        }
    }
}

// ---------------------------------------------------------------------------
// Aggregation, 2 edges per wave-instruction:
//   lane = [edge parity (lane>>5)] [plane ((lane>>4)&1)] [feature group (lane&15)]
// Each lane loads uint2 = 4 fp16 features (8 B) -> one edge covered by 32
// lanes, 2 edges per 64-lane VMEM instruction. f32 accumulation in float4,
// 2 independent chains (4 edges in flight). Epilogue: shfl_xor(32) combines
// edge halves; lanes 0-31 finish (plane0 = z on lanes 0-15, x on 16-31).
// ---------------------------------------------------------------------------
#define GATHER_ADD(S, C)                                       \
    {                                                          \
        union { uint2 u; __half2 h2[2]; } g_;                  \
        g_.u = *(const uint2*)(Hp + (size_t)(C) * 64);         \
        float2 a_ = __half22float2(g_.h2[0]);                  \
        float2 b_ = __half22float2(g_.h2[1]);                  \
        S.x += a_.x; S.y += a_.y; S.z += b_.x; S.w += b_.y;    \
    }

#define AGG_LOOP()                                                          \
    int beg = rowp[i], end = rowp[i + 1];                                   \
    float4 s0 = {0.f, 0.f, 0.f, 0.f}, s1 = {0.f, 0.f, 0.f, 0.f};           \
    int p = beg;                                                            \
    if ((p & 1) && p < end) {                                               \
        if (lane < 32) { int c = csrc[p]; GATHER_ADD(s0, c); }              \
        p++;                                                                \
    }                                                                       \
    for (; p + 4 <= end; p += 4) {                                          \
        int2 c01 = *(const int2*)(csrc + p);                                \
        int2 c23 = *(const int2*)(csrc + p + 2);                            \
        int cA = (lane < 32) ? c01.x : c01.y;                               \
        int cB = (lane < 32) ? c23.x : c23.y;                               \
        GATHER_ADD(s0, cA);                                                 \
        GATHER_ADD(s1, cB);                                                 \
    }                                                                       \
    if (p + 2 <= end) {                                                     \
        int2 c01 = *(const int2*)(csrc + p);                                \
        int cA = (lane < 32) ? c01.x : c01.y;                               \
        GATHER_ADD(s0, cA);                                                 \
        p += 2;                                                             \
    }                                                                       \
    if (p < end) {                                                          \
        if (lane < 32) { int c = csrc[p]; GATHER_ADD(s1, c); }              \
    }                                                                       \
    float4 s;                                                               \
    s.x = s0.x + s1.x; s.y = s0.y + s1.y;                                   \
    s.z = s0.z + s1.z; s.w = s0.w + s1.w;                                   \
    s.x += __shfl_xor(s.x, 32, 64);                                         \
    s.y += __shfl_xor(s.y, 32, 64);                                         \
    s.z += __shfl_xor(s.z, 32, 64);                                         \
    s.w += __shfl_xor(s.w, 32, 64);

__global__ __launch_bounds__(256) void k_agg_act(
    const int* __restrict__ rowp, const int* __restrict__ csrc,
    const float* __restrict__ dinv, const __half* __restrict__ Hh, int N,
    const float* __restrict__ bz, const float* __restrict__ bx,
    __half* __restrict__ azh, __half* __restrict__ axh) {
    int wid = threadIdx.x >> 6, lane = threadIdx.x & 63;
    int i = blockIdx.x * 4 + wid;
    if (i >= N) return;
    int f0 = (lane & 15) * 4;                       // feature group
    int plane = (lane >> 4) & 1;                    // 0 = z, 1 = x
    const __half* Hp = Hh + (size_t)plane * N * 64 + f0;
    AGG_LOOP();

    if (lane < 32) {
        float4 sl = {0.f, 0.f, 0.f, 0.f};
        GATHER_ADD(sl, i);  // self-loop (pre-scaled by dinv[i] already)
        float dvi = dinv[i];
        const float* bb = plane ? bx : bz;
        float4 b = *(const float4*)(bb + f0);
        float r0 = fmaf(dvi, s.x + sl.x, b.x);
        float r1 = fmaf(dvi, s.y + sl.y, b.y);
        float r2 = fmaf(dvi, s.z + sl.z, b.z);
        float r3 = fmaf(dvi, s.w + sl.w, b.w);
        r0 = r0 >= 0.f ? r0 : r0 * RRELU_SLOPE;
        r1 = r1 >= 0.f ? r1 : r1 * RRELU_SLOPE;
        r2 = r2 >= 0.f ? r2 : r2 * RRELU_SLOPE;
        r3 = r3 >= 0.f ? r3 : r3 * RRELU_SLOPE;
        __half* ap = plane ? axh : azh;
        union { __half2 h2[2]; uint2 u; } pk;
        pk.h2[0] = __floats2half2_rn(r0, r1);
        pk.h2[1] = __floats2half2_rn(r2, r3);
        *(uint2*)(ap + (size_t)i * 64 + f0) = pk.u;
    }
}

__global__ __launch_bounds__(256) void k_agg_final(
    const int* __restrict__ rowp, const int* __restrict__ csrc,
    const float* __restrict__ dinv, const __half* __restrict__ Hh, int N,
    const float* __restrict__ bz, const float* __restrict__ bx,
    const float* __restrict__ Wout, const float* __restrict__ bout,
    float* __restrict__ out) {
    int wid = threadIdx.x >> 6, lane = threadIdx.x & 63;
    int i = blockIdx.x * 4 + wid;
    if (i >= N) return;
    int f0 = (lane & 15) * 4;
    int plane = (lane >> 4) & 1;
    const __half* Hp = Hh + (size_t)plane * N * 64 + f0;
    AGG_LOOP();

    float4 sl = {0.f, 0.f, 0.f, 0.f};
    if (lane < 32) GATHER_ADD(sl, i);
    float dvi = dinv[i];
    const float* bb = plane ? bx : bz;
    float4 b = *(const float4*)(bb + f0);
    float t0 = tanhf(fmaf(dvi, s.x + sl.x, b.x));
    float t1 = tanhf(fmaf(dvi, s.y + sl.y, b.y));
    float t2 = tanhf(fmaf(dvi, s.z + sl.z, b.z));
    float t3 = tanhf(fmaf(dvi, s.w + sl.w, b.w));
    // pair plane0 lane j with plane1 lane j^16 (same features)
    float q0 = __shfl_xor(t0, 16, 64);
    float q1 = __shfl_xor(t1, 16, 64);
    float q2 = __shfl_xor(t2, 16, 64);
    float q3 = __shfl_xor(t3, 16, 64);
    float4 w = *(const float4*)(Wout + f0);
    float prod = t0 * q0 * w.x + t1 * q1 * w.y + t2 * q2 * w.z + t3 * q3 * w.w;
    for (int o = 8; o >= 1; o >>= 1) prod += __shfl_xor(prod, o, 64);
    if (lane == 0) out[i] = prod + bout[0];
}

// ---------------------------------------------------------------------------

extern "C" void kernel_launch(void* const* d_in, const int* in_sizes, int n_in,
                              void* d_out, int out_size, void* d_ws, size_t ws_size,
                              hipStream_t stream) {
    const float* z = (const float*)d_in[0];
    const float* x = (const float*)d_in[1];
    const int* ei = (const int*)d_in[2];
    const float* We1 = (const float*)d_in[3];
    const float* be1 = (const float*)d_in[4];
    const float* We2 = (const float*)d_in[5];
    const float* be2 = (const float*)d_in[6];
    const float* Wf1 = (const float*)d_in[7];
    const float* bf1 = (const float*)d_in[8];
    const float* Wf2 = (const float*)d_in[9];
    const float* bf2 = (const float*)d_in[10];
    const float* Wout = (const float*)d_in[11];
    const float* bout = (const float*)d_in[12];
    float* out = (float*)d_out;

    int N = in_sizes[0] / 128;
    int E = in_sizes[2] / 2;
    const int* src = ei;
    const int* dst = ei + E;

    char* base = (char*)d_ws;
    size_t off = 0;
    auto take = [&](size_t nbytes) -> char* {
        char* p = base + off;
        off = (off + nbytes + 255) & ~(size_t)255;
        return p;
    };
    int NB = (N + 255) / 256;
    int* cnt = (int*)take((size_t)N * 4);
    int* bsum = (int*)take(1024 * 4);
    int* boff = (int*)take(1024 * 4);
    int* rowp = (int*)take(((size_t)N + 1) * 4);
    float* dinv = (float*)take((size_t)N * 4);
    int* rank = (int*)take((size_t)E * 4);
    int* csrc = (int*)take((size_t)E * 4);
    __half* Hh = (__half*)take((size_t)N * 64 * 2 * 2);  // 2 planes fp16
    __half* azh = (__half*)take((size_t)N * 64 * 2);
    __half* axh = (__half*)take((size_t)N * 64 * 2);

    int egrid = (E + 255) / 256;
    k_zero<<<NB, 256, 0, stream>>>(cnt, N);
    k_deg<<<egrid, 256, 0, stream>>>(dst, E, cnt, rank);
    k_scan1<<<NB, 256, 0, stream>>>(cnt, N, bsum);
    k_scan2<<<1, 256, 0, stream>>>(bsum, NB, boff, rowp, N, E);
    k_scan3<<<NB, 256, 0, stream>>>(cnt, boff, N, rowp, dinv);
    k_fill<<<egrid, 256, 0, stream>>>(src, dst, rank, E, rowp, csrc);

    dim3 mmgrid((N + 63) / 64, 2);
    int agrid = (N + 3) / 4;

    k_mm1<<<mmgrid, 256, 0, stream>>>(z, x, We1, Wf1, dinv, Hh, N);
    k_agg_act<<<agrid, 256, 0, stream>>>(rowp, csrc, dinv, Hh, N, be1, bf1, azh, axh);
    k_mm2h<<<mmgrid, 256, 0, stream>>>(azh, axh, We2, Wf2, dinv, Hh, N);
    k_agg_final<<<agrid, 256, 0, stream>>>(rowp, csrc, dinv, Hh, N, be2, bf2, Wout,
                                           bout, out);
}

// Round 12
// 189.957 us; speedup vs baseline: 2.4018x; 1.0280x over previous
//
#include <hip/hip_runtime.h>
#include <hip/hip_fp16.h>
#include <math.h>

#define RRELU_SLOPE 0.22916667f  // (1/8 + 1/3)/2 = 11/48

// ---------------------------------------------------------------------------
// CSR build: zero -> histogram(+rank) -> scan -> rank-based scatter
// ---------------------------------------------------------------------------

__global__ __launch_bounds__(256) void k_zero(int* __restrict__ cnt, int N) {
    int i = blockIdx.x * 256 + threadIdx.x;
    if (i < N) cnt[i] = 0;
}

__global__ __launch_bounds__(256) void k_deg(const int* __restrict__ dst, int E,
                                             int* __restrict__ cnt,
                                             int* __restrict__ rank) {
    int e = blockIdx.x * 256 + threadIdx.x;
    if (e < E) rank[e] = atomicAdd(&cnt[dst[e]], 1);
}

__global__ __launch_bounds__(256) void k_scan1(const int* __restrict__ cnt, int N,
                                               int* __restrict__ bsum) {
    int i = blockIdx.x * 256 + threadIdx.x;
    int v = (i < N) ? cnt[i] : 0;
    for (int o = 32; o >= 1; o >>= 1) v += __shfl_xor(v, o, 64);
    __shared__ int ws[4];
    if ((threadIdx.x & 63) == 0) ws[threadIdx.x >> 6] = v;
    __syncthreads();
    if (threadIdx.x == 0) bsum[blockIdx.x] = ws[0] + ws[1] + ws[2] + ws[3];
}

__global__ __launch_bounds__(256) void k_scan2(const int* __restrict__ bsum, int NB,
                                               int* __restrict__ boff,
                                               int* __restrict__ rowp, int N, int E) {
    __shared__ int s[256];
    int t = threadIdx.x;
    int v[4];
    int loc = 0;
    for (int i = 0; i < 4; i++) {
        int idx = t * 4 + i;
        v[i] = (idx < NB) ? bsum[idx] : 0;
        loc += v[i];
    }
    s[t] = loc;
    __syncthreads();
    for (int o = 1; o < 256; o <<= 1) {
        int u = (t >= o) ? s[t - o] : 0;
        __syncthreads();
        s[t] += u;
        __syncthreads();
    }
    int excl = s[t] - loc;
    for (int i = 0; i < 4; i++) {
        int idx = t * 4 + i;
        if (idx < NB) { boff[idx] = excl; excl += v[i]; }
    }
    if (t == 0) rowp[N] = E;
}

__global__ __launch_bounds__(256) void k_scan3(const int* __restrict__ cnt,
                                               const int* __restrict__ boff, int N,
                                               int* __restrict__ rowp,
                                               float* __restrict__ dinv) {
    int i = blockIdx.x * 256 + threadIdx.x;
    int lane = threadIdx.x & 63, wid = threadIdx.x >> 6;
    int v = (i < N) ? cnt[i] : 0;
    int inc = v;
    for (int o = 1; o < 64; o <<= 1) {
        int u = __shfl_up(inc, o, 64);
        if (lane >= o) inc += u;
    }
    __shared__ int wsum[4];
    if (lane == 63) wsum[wid] = inc;
    __syncthreads();
    int wo = 0;
    for (int w = 0; w < wid; w++) wo += wsum[w];
    if (i < N) {
        int excl = inc - v + wo + boff[blockIdx.x];
        rowp[i] = excl;
        dinv[i] = 1.0f / sqrtf((float)v + 1.0f);
    }
}

__global__ __launch_bounds__(256) void k_fill(const int* __restrict__ src,
                                              const int* __restrict__ dst,
                                              const int* __restrict__ rank, int E,
                                              const int* __restrict__ rowp,
                                              int* __restrict__ csrc) {
    int e = blockIdx.x * 256 + threadIdx.x;
    if (e >= E) return;
    int d = dst[e];
    csrc[rowp[d] + rank[e]] = src[e];
}

// ---------------------------------------------------------------------------
// Layer-1 matmul (f32 A, K=128), one branch per block (blockIdx.y):
// Hh' = fp16(dinv[r] * (A @ W)). 64x64 tile, 4x4 register micro-kernel.
// ---------------------------------------------------------------------------
__global__ __launch_bounds__(256) void k_mm1(const float* __restrict__ A0,
                                             const float* __restrict__ A1,
                                             const float* __restrict__ W0,
                                             const float* __restrict__ W1,
                                             const float* __restrict__ dinv,
                                             __half* __restrict__ Hh, int N) {
    const float* A = blockIdx.y ? A1 : A0;
    const float* W = blockIdx.y ? W1 : W0;
    __half* H = Hh + (size_t)blockIdx.y * N * 64;

    __shared__ float As[64][20];
    __shared__ float Ws[16][64];

    const int tid = threadIdx.x;
    const int tc = tid & 15, tr = tid >> 4;
    const int row0 = blockIdx.x * 64;
    const int srow = tid >> 2, sk = (tid & 3) * 4;
    const int wk = tid >> 4, wc = (tid & 15) * 4;

    float acc[4][4] = {};

    for (int k0 = 0; k0 < 128; k0 += 16) {
        float4 av = make_float4(0.f, 0.f, 0.f, 0.f);
        int gr = row0 + srow;
        if (gr < N) av = *(const float4*)(A + (size_t)gr * 128 + k0 + sk);
        float4 wv = *(const float4*)(W + (size_t)(k0 + wk) * 64 + wc);
        __syncthreads();
        *(float4*)&As[srow][sk] = av;
        *(float4*)&Ws[wk][wc] = wv;
        __syncthreads();

#pragma unroll
        for (int k = 0; k < 16; k += 4) {
            float4 a4[4], w4[4];
#pragma unroll
            for (int i = 0; i < 4; i++) a4[i] = *(const float4*)&As[tr * 4 + i][k];
#pragma unroll
            for (int kk = 0; kk < 4; kk++) w4[kk] = *(const float4*)&Ws[k + kk][tc * 4];
#pragma unroll
            for (int i = 0; i < 4; i++) {
                const float* ap = (const float*)&a4[i];
#pragma unroll
                for (int kk = 0; kk < 4; kk++) {
                    const float* wp = (const float*)&w4[kk];
                    float a = ap[kk];
                    acc[i][0] = fmaf(a, wp[0], acc[i][0]);
                    acc[i][1] = fmaf(a, wp[1], acc[i][1]);
                    acc[i][2] = fmaf(a, wp[2], acc[i][2]);
                    acc[i][3] = fmaf(a, wp[3], acc[i][3]);
                }
            }
        }
    }

#pragma unroll
    for (int i = 0; i < 4; i++) {
        int r = row0 + tr * 4 + i;
        if (r < N) {
            float dv = dinv[r];
            union { __half2 h2[2]; uint2 u; } pk;
            pk.h2[0] = __floats2half2_rn(acc[i][0] * dv, acc[i][1] * dv);
            pk.h2[1] = __floats2half2_rn(acc[i][2] * dv, acc[i][3] * dv);
            *(uint2*)(H + (size_t)r * 64 + tc * 4) = pk.u;
        }
    }
}

// ---------------------------------------------------------------------------
// Layer-2 matmul: fp16 A planes (K=64), f32 W; fp16 output like k_mm1.
// ---------------------------------------------------------------------------
__global__ __launch_bounds__(256) void k_mm2h(const __half* __restrict__ A0,
                                              const __half* __restrict__ A1,
                                              const float* __restrict__ W0,
                                              const float* __restrict__ W1,
                                              const float* __restrict__ dinv,
                                              __half* __restrict__ Hh, int N) {
    const __half* A = blockIdx.y ? A1 : A0;
    const float* W = blockIdx.y ? W1 : W0;
    __half* H = Hh + (size_t)blockIdx.y * N * 64;

    __shared__ float As[64][20];
    __shared__ float Ws[16][64];

    const int tid = threadIdx.x;
    const int tc = tid & 15, tr = tid >> 4;
    const int row0 = blockIdx.x * 64;
    const int srow = tid >> 2, sk = (tid & 3) * 4;
    const int wk = tid >> 4, wc = (tid & 15) * 4;

    float acc[4][4] = {};

    for (int k0 = 0; k0 < 64; k0 += 16) {
        float4 av = make_float4(0.f, 0.f, 0.f, 0.f);
        int gr = row0 + srow;
        if (gr < N) {
            union { uint2 u; __half2 h2[2]; } cu;
            cu.u = *(const uint2*)(A + (size_t)gr * 64 + k0 + sk);
            float2 f01 = __half22float2(cu.h2[0]);
            float2 f23 = __half22float2(cu.h2[1]);
            av = make_float4(f01.x, f01.y, f23.x, f23.y);
        }
        float4 wv = *(const float4*)(W + (size_t)(k0 + wk) * 64 + wc);
        __syncthreads();
        *(float4*)&As[srow][sk] = av;
        *(float4*)&Ws[wk][wc] = wv;
        __syncthreads();

#pragma unroll
        for (int k = 0; k < 16; k += 4) {
            float4 a4[4], w4[4];
#pragma unroll
            for (int i = 0; i < 4; i++) a4[i] = *(const float4*)&As[tr * 4 + i][k];
#pragma unroll
            for (int kk = 0; kk < 4; kk++) w4[kk] = *(const float4*)&Ws[k + kk][tc * 4];
#pragma unroll
            for (int i = 0; i < 4; i++) {
                const float* ap = (const float*)&a4[i];
#pragma unroll
                for (int kk = 0; kk < 4; kk++) {
                    const float* wp = (const float*)&w4[kk];
                    float a = ap[kk];
                    acc[i][0] = fmaf(a, wp[0], acc[i][0]);
                    acc[i][1] = fmaf(a, wp[1], acc[i][1]);
                    acc[i][2] = fmaf(a, wp[2], acc[i][2]);
                    acc[i][3] = fmaf(a, wp[3], acc[i][3]);
                }
            }
        }
    }

#pragma unroll
    for (int i = 0; i < 4; i++) {
        int r = row0 + tr * 4 + i;
        if (r < N) {
            float dv = dinv[r];
            union { __half2 h2[2]; uint2 u; } pk;
            pk.h2[0] = __floats2half2_rn(acc[i][0] * dv, acc[i][1] * dv);
            pk.h2[1] = __floats2half2_rn(acc[i][2] * dv, acc[i][3] * dv);
            *(uint2*)(H + (size_t)r * 64 + tc * 4) = pk.u;
        }
    }
}

// ---------------------------------------------------------------------------
// Aggregation, 2 edges per wave-instruction, 8 edges in flight (4 chains):
//   lane = [edge parity (lane>>5)] [plane ((lane>>4)&1)] [feature group (lane&15)]
// Each lane loads uint2 = 4 fp16 features (8 B); 2 edges per VMEM instruction;
// main loop issues 4 independent gather instructions (8 edges, 2 KB in flight).
// Epilogue: shfl_xor(32) combines edge halves.
// ---------------------------------------------------------------------------
#define GATHER_ADD(S, C)                                       \
    {                                                          \
        union { uint2 u; __half2 h2[2]; } g_;                  \
        g_.u = *(const uint2*)(Hp + (size_t)(C) * 64);         \
        float2 a_ = __half22float2(g_.h2[0]);                  \
        float2 b_ = __half22float2(g_.h2[1]);                  \
        S.x += a_.x; S.y += a_.y; S.z += b_.x; S.w += b_.y;    \
    }

#define AGG_LOOP()                                                          \
    int beg = rowp[i], end = rowp[i + 1];                                   \
    float4 s0 = {0.f, 0.f, 0.f, 0.f}, s1 = {0.f, 0.f, 0.f, 0.f};           \
    float4 s2 = {0.f, 0.f, 0.f, 0.f}, s3 = {0.f, 0.f, 0.f, 0.f};           \
    int p = beg;                                                            \
    if ((p & 1) && p < end) {                                               \
        if (lane < 32) { int c = csrc[p]; GATHER_ADD(s0, c); }              \
        p++;                                                                \
    }                                                                       \
    for (; p + 8 <= end; p += 8) {                                          \
        int2 c01 = *(const int2*)(csrc + p);                                \
        int2 c23 = *(const int2*)(csrc + p + 2);                            \
        int2 c45 = *(const int2*)(csrc + p + 4);                            \
        int2 c67 = *(const int2*)(csrc + p + 6);                            \
        int cA = (lane < 32) ? c01.x : c01.y;                               \
        int cB = (lane < 32) ? c23.x : c23.y;                               \
        int cC = (lane < 32) ? c45.x : c45.y;                               \
        int cD = (lane < 32) ? c67.x : c67.y;                               \
        GATHER_ADD(s0, cA);                                                 \
        GATHER_ADD(s1, cB);                                                 \
        GATHER_ADD(s2, cC);                                                 \
        GATHER_ADD(s3, cD);                                                 \
    }                                                                       \
    for (; p + 2 <= end; p += 2) {                                          \
        int2 c01 = *(const int2*)(csrc + p);                                \
        int cA = (lane < 32) ? c01.x : c01.y;                               \
        GATHER_ADD(s0, cA);                                                 \
    }                                                                       \
    if (p < end) {                                                          \
        if (lane < 32) { int c = csrc[p]; GATHER_ADD(s1, c); }              \
    }                                                                       \
    float4 s;                                                               \
    s.x = (s0.x + s1.x) + (s2.x + s3.x);                                    \
    s.y = (s0.y + s1.y) + (s2.y + s3.y);                                    \
    s.z = (s0.z + s1.z) + (s2.z + s3.z);                                    \
    s.w = (s0.w + s1.w) + (s2.w + s3.w);                                    \
    s.x += __shfl_xor(s.x, 32, 64);                                         \
    s.y += __shfl_xor(s.y, 32, 64);                                         \
    s.z += __shfl_xor(s.z, 32, 64);                                         \
    s.w += __shfl_xor(s.w, 32, 64);

__global__ __launch_bounds__(256) void k_agg_act(
    const int* __restrict__ rowp, const int* __restrict__ csrc,
    const float* __restrict__ dinv, const __half* __restrict__ Hh, int N,
    const float* __restrict__ bz, const float* __restrict__ bx,
    __half* __restrict__ azh, __half* __restrict__ axh) {
    int wid = threadIdx.x >> 6, lane = threadIdx.x & 63;
    int i = blockIdx.x * 4 + wid;
    if (i >= N) return;
    int f0 = (lane & 15) * 4;                       // feature group
    int plane = (lane >> 4) & 1;                    // 0 = z, 1 = x
    const __half* Hp = Hh + (size_t)plane * N * 64 + f0;
    AGG_LOOP();

    if (lane < 32) {
        float4 sl = {0.f, 0.f, 0.f, 0.f};
        GATHER_ADD(sl, i);  // self-loop (pre-scaled by dinv[i] already)
        float dvi = dinv[i];
        const float* bb = plane ? bx : bz;
        float4 b = *(const float4*)(bb + f0);
        float r0 = fmaf(dvi, s.x + sl.x, b.x);
        float r1 = fmaf(dvi, s.y + sl.y, b.y);
        float r2 = fmaf(dvi, s.z + sl.z, b.z);
        float r3 = fmaf(dvi, s.w + sl.w, b.w);
        r0 = r0 >= 0.f ? r0 : r0 * RRELU_SLOPE;
        r1 = r1 >= 0.f ? r1 : r1 * RRELU_SLOPE;
        r2 = r2 >= 0.f ? r2 : r2 * RRELU_SLOPE;
        r3 = r3 >= 0.f ? r3 : r3 * RRELU_SLOPE;
        __half* ap = plane ? axh : azh;
        union { __half2 h2[2]; uint2 u; } pk;
        pk.h2[0] = __floats2half2_rn(r0, r1);
        pk.h2[1] = __floats2half2_rn(r2, r3);
        *(uint2*)(ap + (size_t)i * 64 + f0) = pk.u;
    }
}

__global__ __launch_bounds__(256) void k_agg_final(
    const int* __restrict__ rowp, const int* __restrict__ csrc,
    const float* __restrict__ dinv, const __half* __restrict__ Hh, int N,
    const float* __restrict__ bz, const float* __restrict__ bx,
    const float* __restrict__ Wout, const float* __restrict__ bout,
    float* __restrict__ out) {
    int wid = threadIdx.x >> 6, lane = threadIdx.x & 63;
    int i = blockIdx.x * 4 + wid;
    if (i >= N) return;
    int f0 = (lane & 15) * 4;
    int plane = (lane >> 4) & 1;
    const __half* Hp = Hh + (size_t)plane * N * 64 + f0;
    AGG_LOOP();

    float4 sl = {0.f, 0.f, 0.f, 0.f};
    if (lane < 32) GATHER_ADD(sl, i);
    float dvi = dinv[i];
    const float* bb = plane ? bx : bz;
    float4 b = *(const float4*)(bb + f0);
    float t0 = tanhf(fmaf(dvi, s.x + sl.x, b.x));
    float t1 = tanhf(fmaf(dvi, s.y + sl.y, b.y));
    float t2 = tanhf(fmaf(dvi, s.z + sl.z, b.z));
    float t3 = tanhf(fmaf(dvi, s.w + sl.w, b.w));
    // pair plane0 lane j with plane1 lane j^16 (same features)
    float q0 = __shfl_xor(t0, 16, 64);
    float q1 = __shfl_xor(t1, 16, 64);
    float q2 = __shfl_xor(t2, 16, 64);
    float q3 = __shfl_xor(t3, 16, 64);
    float4 w = *(const float4*)(Wout + f0);
    float prod = t0 * q0 * w.x + t1 * q1 * w.y + t2 * q2 * w.z + t3 * q3 * w.w;
    for (int o = 8; o >= 1; o >>= 1) prod += __shfl_xor(prod, o, 64);
    if (lane == 0) out[i] = prod + bout[0];
}

// ---------------------------------------------------------------------------

extern "C" void kernel_launch(void* const* d_in, const int* in_sizes, int n_in,
                              void* d_out, int out_size, void* d_ws, size_t ws_size,
                              hipStream_t stream) {
    const float* z = (const float*)d_in[0];
    const float* x = (const float*)d_in[1];
    const int* ei = (const int*)d_in[2];
    const float* We1 = (const float*)d_in[3];
    const float* be1 = (const float*)d_in[4];
    const float* We2 = (const float*)d_in[5];
    const float* be2 = (const float*)d_in[6];
    const float* Wf1 = (const float*)d_in[7];
    const float* bf1 = (const float*)d_in[8];
    const float* Wf2 = (const float*)d_in[9];
    const float* bf2 = (const float*)d_in[10];
    const float* Wout = (const float*)d_in[11];
    const float* bout = (const float*)d_in[12];
    float* out = (float*)d_out;

    int N = in_sizes[0] / 128;
    int E = in_sizes[2] / 2;
    const int* src = ei;
    const int* dst = ei + E;

    char* base = (char*)d_ws;
    size_t off = 0;
    auto take = [&](size_t nbytes) -> char* {
        char* p = base + off;
        off = (off + nbytes + 255) & ~(size_t)255;
        return p;
    };
    int NB = (N + 255) / 256;
    int* cnt = (int*)take((size_t)N * 4);
    int* bsum = (int*)take(1024 * 4);
    int* boff = (int*)take(1024 * 4);
    int* rowp = (int*)take(((size_t)N + 1) * 4);
    float* dinv = (float*)take((size_t)N * 4);
    int* rank = (int*)take((size_t)E * 4);
    int* csrc = (int*)take((size_t)E * 4);
    __half* Hh = (__half*)take((size_t)N * 64 * 2 * 2);  // 2 planes fp16
    __half* azh = (__half*)take((size_t)N * 64 * 2);
    __half* axh = (__half*)take((size_t)N * 64 * 2);

    int egrid = (E + 255) / 256;
    k_zero<<<NB, 256, 0, stream>>>(cnt, N);
    k_deg<<<egrid, 256, 0, stream>>>(dst, E, cnt, rank);
    k_scan1<<<NB, 256, 0, stream>>>(cnt, N, bsum);
    k_scan2<<<1, 256, 0, stream>>>(bsum, NB, boff, rowp, N, E);
    k_scan3<<<NB, 256, 0, stream>>>(cnt, boff, N, rowp, dinv);
    k_fill<<<egrid, 256, 0, stream>>>(src, dst, rank, E, rowp, csrc);

    dim3 mmgrid((N + 63) / 64, 2);
    int agrid = (N + 3) / 4;

    k_mm1<<<mmgrid, 256, 0, stream>>>(z, x, We1, Wf1, dinv, Hh, N);
    k_agg_act<<<agrid, 256, 0, stream>>>(rowp, csrc, dinv, Hh, N, be1, bf1, azh, axh);
    k_mm2h<<<mmgrid, 256, 0, stream>>>(azh, axh, We2, Wf2, dinv, Hh, N);
    k_agg_final<<<agrid, 256, 0, stream>>>(rowp, csrc, dinv, Hh, N, be2, bf2, Wout,
                                           bout, out);
}

// Round 13
// 186.779 us; speedup vs baseline: 2.4426x; 1.0170x over previous
//
#include <hip/hip_runtime.h>
#include <hip/hip_fp16.h>
#include <math.h>

#define RRELU_SLOPE 0.22916667f  // (1/8 + 1/3)/2 = 11/48

// ---------------------------------------------------------------------------
// CSR build: zero -> histogram(+rank) -> scan -> rank-based scatter
// ---------------------------------------------------------------------------

__global__ __launch_bounds__(256) void k_zero(int* __restrict__ cnt, int N) {
    int i = blockIdx.x * 256 + threadIdx.x;
    if (i < N) cnt[i] = 0;
}

__global__ __launch_bounds__(256) void k_deg(const int* __restrict__ dst, int E,
                                             int* __restrict__ cnt,
                                             int* __restrict__ rank) {
    int e = blockIdx.x * 256 + threadIdx.x;
    if (e < E) rank[e] = atomicAdd(&cnt[dst[e]], 1);
}

__global__ __launch_bounds__(256) void k_scan1(const int* __restrict__ cnt, int N,
                                               int* __restrict__ bsum) {
    int i = blockIdx.x * 256 + threadIdx.x;
    int v = (i < N) ? cnt[i] : 0;
    for (int o = 32; o >= 1; o >>= 1) v += __shfl_xor(v, o, 64);
    __shared__ int ws[4];
    if ((threadIdx.x & 63) == 0) ws[threadIdx.x >> 6] = v;
    __syncthreads();
    if (threadIdx.x == 0) bsum[blockIdx.x] = ws[0] + ws[1] + ws[2] + ws[3];
}

__global__ __launch_bounds__(256) void k_scan2(const int* __restrict__ bsum, int NB,
                                               int* __restrict__ boff,
                                               int* __restrict__ rowp, int N, int E) {
    __shared__ int s[256];
    int t = threadIdx.x;
    int v[4];
    int loc = 0;
    for (int i = 0; i < 4; i++) {
        int idx = t * 4 + i;
        v[i] = (idx < NB) ? bsum[idx] : 0;
        loc += v[i];
    }
    s[t] = loc;
    __syncthreads();
    for (int o = 1; o < 256; o <<= 1) {
        int u = (t >= o) ? s[t - o] : 0;
        __syncthreads();
        s[t] += u;
        __syncthreads();
    }
    int excl = s[t] - loc;
    for (int i = 0; i < 4; i++) {
        int idx = t * 4 + i;
        if (idx < NB) { boff[idx] = excl; excl += v[i]; }
    }
    if (t == 0) rowp[N] = E;
}

__global__ __launch_bounds__(256) void k_scan3(const int* __restrict__ cnt,
                                               const int* __restrict__ boff, int N,
                                               int* __restrict__ rowp,
                                               float* __restrict__ dinv) {
    int i = blockIdx.x * 256 + threadIdx.x;
    int lane = threadIdx.x & 63, wid = threadIdx.x >> 6;
    int v = (i < N) ? cnt[i] : 0;
    int inc = v;
    for (int o = 1; o < 64; o <<= 1) {
        int u = __shfl_up(inc, o, 64);
        if (lane >= o) inc += u;
    }
    __shared__ int wsum[4];
    if (lane == 63) wsum[wid] = inc;
    __syncthreads();
    int wo = 0;
    for (int w = 0; w < wid; w++) wo += wsum[w];
    if (i < N) {
        int excl = inc - v + wo + boff[blockIdx.x];
        rowp[i] = excl;
        dinv[i] = 1.0f / sqrtf((float)v + 1.0f);
    }
}

__global__ __launch_bounds__(256) void k_fill(const int* __restrict__ src,
                                              const int* __restrict__ dst,
                                              const int* __restrict__ rank, int E,
                                              const int* __restrict__ rowp,
                                              int* __restrict__ csrc) {
    int e = blockIdx.x * 256 + threadIdx.x;
    if (e >= E) return;
    int d = dst[e];
    csrc[rowp[d] + rank[e]] = src[e];
}

// ---------------------------------------------------------------------------
// Layer-1 matmul (f32 A, K=128), one branch per block (blockIdx.y):
// H' = fp16(dinv[r] * (A @ W)), interleaved layout H[r][branch*64 + f].
// 64x64 tile, 4x4 register micro-kernel.
// ---------------------------------------------------------------------------
__global__ __launch_bounds__(256) void k_mm1(const float* __restrict__ A0,
                                             const float* __restrict__ A1,
                                             const float* __restrict__ W0,
                                             const float* __restrict__ W1,
                                             const float* __restrict__ dinv,
                                             __half* __restrict__ Hh, int N) {
    const float* A = blockIdx.y ? A1 : A0;
    const float* W = blockIdx.y ? W1 : W0;
    __half* H = Hh + blockIdx.y * 64;  // row stride 128

    __shared__ float As[64][20];
    __shared__ float Ws[16][64];

    const int tid = threadIdx.x;
    const int tc = tid & 15, tr = tid >> 4;
    const int row0 = blockIdx.x * 64;
    const int srow = tid >> 2, sk = (tid & 3) * 4;
    const int wk = tid >> 4, wc = (tid & 15) * 4;

    float acc[4][4] = {};

    for (int k0 = 0; k0 < 128; k0 += 16) {
        float4 av = make_float4(0.f, 0.f, 0.f, 0.f);
        int gr = row0 + srow;
        if (gr < N) av = *(const float4*)(A + (size_t)gr * 128 + k0 + sk);
        float4 wv = *(const float4*)(W + (size_t)(k0 + wk) * 64 + wc);
        __syncthreads();
        *(float4*)&As[srow][sk] = av;
        *(float4*)&Ws[wk][wc] = wv;
        __syncthreads();

#pragma unroll
        for (int k = 0; k < 16; k += 4) {
            float4 a4[4], w4[4];
#pragma unroll
            for (int i = 0; i < 4; i++) a4[i] = *(const float4*)&As[tr * 4 + i][k];
#pragma unroll
            for (int kk = 0; kk < 4; kk++) w4[kk] = *(const float4*)&Ws[k + kk][tc * 4];
#pragma unroll
            for (int i = 0; i < 4; i++) {
                const float* ap = (const float*)&a4[i];
#pragma unroll
                for (int kk = 0; kk < 4; kk++) {
                    const float* wp = (const float*)&w4[kk];
                    float a = ap[kk];
                    acc[i][0] = fmaf(a, wp[0], acc[i][0]);
                    acc[i][1] = fmaf(a, wp[1], acc[i][1]);
                    acc[i][2] = fmaf(a, wp[2], acc[i][2]);
                    acc[i][3] = fmaf(a, wp[3], acc[i][3]);
                }
            }
        }
    }

#pragma unroll
    for (int i = 0; i < 4; i++) {
        int r = row0 + tr * 4 + i;
        if (r < N) {
            float dv = dinv[r];
            union { __half2 h2[2]; uint2 u; } pk;
            pk.h2[0] = __floats2half2_rn(acc[i][0] * dv, acc[i][1] * dv);
            pk.h2[1] = __floats2half2_rn(acc[i][2] * dv, acc[i][3] * dv);
            *(uint2*)(H + (size_t)r * 128 + tc * 4) = pk.u;
        }
    }
}

// ---------------------------------------------------------------------------
// Layer-2 matmul: fp16 A planes (K=64), f32 W; interleaved fp16 output.
// ---------------------------------------------------------------------------
__global__ __launch_bounds__(256) void k_mm2h(const __half* __restrict__ A0,
                                              const __half* __restrict__ A1,
                                              const float* __restrict__ W0,
                                              const float* __restrict__ W1,
                                              const float* __restrict__ dinv,
                                              __half* __restrict__ Hh, int N) {
    const __half* A = blockIdx.y ? A1 : A0;
    const float* W = blockIdx.y ? W1 : W0;
    __half* H = Hh + blockIdx.y * 64;  // row stride 128

    __shared__ float As[64][20];
    __shared__ float Ws[16][64];

    const int tid = threadIdx.x;
    const int tc = tid & 15, tr = tid >> 4;
    const int row0 = blockIdx.x * 64;
    const int srow = tid >> 2, sk = (tid & 3) * 4;
    const int wk = tid >> 4, wc = (tid & 15) * 4;

    float acc[4][4] = {};

    for (int k0 = 0; k0 < 64; k0 += 16) {
        float4 av = make_float4(0.f, 0.f, 0.f, 0.f);
        int gr = row0 + srow;
        if (gr < N) {
            union { uint2 u; __half2 h2[2]; } cu;
            cu.u = *(const uint2*)(A + (size_t)gr * 64 + k0 + sk);
            float2 f01 = __half22float2(cu.h2[0]);
            float2 f23 = __half22float2(cu.h2[1]);
            av = make_float4(f01.x, f01.y, f23.x, f23.y);
        }
        float4 wv = *(const float4*)(W + (size_t)(k0 + wk) * 64 + wc);
        __syncthreads();
        *(float4*)&As[srow][sk] = av;
        *(float4*)&Ws[wk][wc] = wv;
        __syncthreads();

#pragma unroll
        for (int k = 0; k < 16; k += 4) {
            float4 a4[4], w4[4];
#pragma unroll
            for (int i = 0; i < 4; i++) a4[i] = *(const float4*)&As[tr * 4 + i][k];
#pragma unroll
            for (int kk = 0; kk < 4; kk++) w4[kk] = *(const float4*)&Ws[k + kk][tc * 4];
#pragma unroll
            for (int i = 0; i < 4; i++) {
                const float* ap = (const float*)&a4[i];
#pragma unroll
                for (int kk = 0; kk < 4; kk++) {
                    const float* wp = (const float*)&w4[kk];
                    float a = ap[kk];
                    acc[i][0] = fmaf(a, wp[0], acc[i][0]);
                    acc[i][1] = fmaf(a, wp[1], acc[i][1]);
                    acc[i][2] = fmaf(a, wp[2], acc[i][2]);
                    acc[i][3] = fmaf(a, wp[3], acc[i][3]);
                }
            }
        }
    }

#pragma unroll
    for (int i = 0; i < 4; i++) {
        int r = row0 + tr * 4 + i;
        if (r < N) {
            float dv = dinv[r];
            union { __half2 h2[2]; uint2 u; } pk;
            pk.h2[0] = __floats2half2_rn(acc[i][0] * dv, acc[i][1] * dv);
            pk.h2[1] = __floats2half2_rn(acc[i][2] * dv, acc[i][3] * dv);
            *(uint2*)(H + (size_t)r * 128 + tc * 4) = pk.u;
        }
    }
}

// ---------------------------------------------------------------------------
// Aggregation over interleaved fp16 H [N][128] (z cols 0-63, x cols 64-127).
// 4 edges per VMEM instruction: lane = [edge e (lane>>4)] [plane h ((lane>>3)&1)]
// [feature group g (lane&7), 8 features]. Each lane loads uint4 (16 B);
// one edge = 16 lanes = 256 B contiguous. Main loop 16 edges / 4 chains
// (4 KB in flight). csrc read as per-lane broadcast dword (1 line / 4 edges).
// Reduction over e: shfl_xor 16, 32.
// ---------------------------------------------------------------------------
#define GATHER_ADD8(S, C)                                      \
    {                                                          \
        union { uint4 u; __half2 h2[4]; } g_;                  \
        g_.u = *(const uint4*)(Hp + (size_t)(C) * 128);        \
        float2 f0_ = __half22float2(g_.h2[0]);                 \
        float2 f1_ = __half22float2(g_.h2[1]);                 \
        float2 f2_ = __half22float2(g_.h2[2]);                 \
        float2 f3_ = __half22float2(g_.h2[3]);                 \
        S[0] += f0_.x; S[1] += f0_.y; S[2] += f1_.x;           \
        S[3] += f1_.y; S[4] += f2_.x; S[5] += f2_.y;           \
        S[6] += f3_.x; S[7] += f3_.y;                          \
    }

#define AGG_LOOP()                                                          \
    int beg = rowp[i], end = rowp[i + 1];                                   \
    float s0[8] = {}, s1[8] = {}, s2[8] = {}, s3[8] = {};                   \
    int p = beg;                                                            \
    for (; p + 16 <= end; p += 16) {                                        \
        int cA = csrc[p + e];                                               \
        int cB = csrc[p + 4 + e];                                           \
        int cC = csrc[p + 8 + e];                                           \
        int cD = csrc[p + 12 + e];                                          \
        GATHER_ADD8(s0, cA);                                                \
        GATHER_ADD8(s1, cB);                                                \
        GATHER_ADD8(s2, cC);                                                \
        GATHER_ADD8(s3, cD);                                                \
    }                                                                       \
    for (; p + 8 <= end; p += 8) {                                          \
        int cA = csrc[p + e];                                               \
        int cB = csrc[p + 4 + e];                                           \
        GATHER_ADD8(s0, cA);                                                \
        GATHER_ADD8(s1, cB);                                                \
    }                                                                       \
    if (p + 4 <= end) {                                                     \
        int cA = csrc[p + e];                                               \
        GATHER_ADD8(s0, cA);                                                \
        p += 4;                                                             \
    }                                                                       \
    {                                                                       \
        int rem = end - p;                                                  \
        if (rem > 0) {                                                      \
            int c = csrc[p + ((e < rem) ? e : 0)];                          \
            if (e < rem) GATHER_ADD8(s1, c);                                \
        }                                                                   \
    }                                                                       \
    float s[8];                                                             \
    _Pragma("unroll")                                                       \
    for (int k = 0; k < 8; k++)                                             \
        s[k] = (s0[k] + s1[k]) + (s2[k] + s3[k]);                           \
    _Pragma("unroll")                                                       \
    for (int k = 0; k < 8; k++) s[k] += __shfl_xor(s[k], 16, 64);           \
    _Pragma("unroll")                                                       \
    for (int k = 0; k < 8; k++) s[k] += __shfl_xor(s[k], 32, 64);

__global__ __launch_bounds__(256) void k_agg_act(
    const int* __restrict__ rowp, const int* __restrict__ csrc,
    const float* __restrict__ dinv, const __half* __restrict__ Hh, int N,
    const float* __restrict__ bz, const float* __restrict__ bx,
    __half* __restrict__ azh, __half* __restrict__ axh) {
    int wid = threadIdx.x >> 6, lane = threadIdx.x & 63;
    int i = blockIdx.x * 4 + wid;
    if (i >= N) return;
    int g = lane & 7;            // feature group (8 features)
    int h = (lane >> 3) & 1;     // 0 = z, 1 = x
    int e = lane >> 4;           // edge slot 0..3
    const __half* Hp = Hh + h * 64 + g * 8;
    AGG_LOOP();

    if (e == 0) {
        float sl[8] = {};
        GATHER_ADD8(sl, i);  // self-loop (pre-scaled by dinv[i])
        float dvi = dinv[i];
        const float* bb = h ? bx : bz;
        float4 b0 = *(const float4*)(bb + g * 8);
        float4 b1 = *(const float4*)(bb + g * 8 + 4);
        float r[8];
        const float* bp = (const float*)&b0;
#pragma unroll
        for (int k = 0; k < 4; k++) r[k] = fmaf(dvi, s[k] + sl[k], bp[k]);
        bp = (const float*)&b1;
#pragma unroll
        for (int k = 0; k < 4; k++) r[4 + k] = fmaf(dvi, s[4 + k] + sl[4 + k], bp[k]);
#pragma unroll
        for (int k = 0; k < 8; k++) r[k] = r[k] >= 0.f ? r[k] : r[k] * RRELU_SLOPE;
        __half* ap = h ? axh : azh;
        union { __half2 h2[4]; uint4 u; } pk;
        pk.h2[0] = __floats2half2_rn(r[0], r[1]);
        pk.h2[1] = __floats2half2_rn(r[2], r[3]);
        pk.h2[2] = __floats2half2_rn(r[4], r[5]);
        pk.h2[3] = __floats2half2_rn(r[6], r[7]);
        *(uint4*)(ap + (size_t)i * 64 + g * 8) = pk.u;
    }
}

__global__ __launch_bounds__(256) void k_agg_final(
    const int* __restrict__ rowp, const int* __restrict__ csrc,
    const float* __restrict__ dinv, const __half* __restrict__ Hh, int N,
    const float* __restrict__ bz, const float* __restrict__ bx,
    const float* __restrict__ Wout, const float* __restrict__ bout,
    float* __restrict__ out) {
    int wid = threadIdx.x >> 6, lane = threadIdx.x & 63;
    int i = blockIdx.x * 4 + wid;
    if (i >= N) return;
    int g = lane & 7;
    int h = (lane >> 3) & 1;
    int e = lane >> 4;
    const __half* Hp = Hh + h * 64 + g * 8;
    AGG_LOOP();

    float sl[8] = {};
    GATHER_ADD8(sl, i);
    float dvi = dinv[i];
    const float* bb = h ? bx : bz;
    float4 b0 = *(const float4*)(bb + g * 8);
    float4 b1 = *(const float4*)(bb + g * 8 + 4);
    float t[8];
    const float* bp = (const float*)&b0;
#pragma unroll
    for (int k = 0; k < 4; k++) t[k] = tanhf(fmaf(dvi, s[k] + sl[k], bp[k]));
    bp = (const float*)&b1;
#pragma unroll
    for (int k = 0; k < 4; k++)
        t[4 + k] = tanhf(fmaf(dvi, s[4 + k] + sl[4 + k], bp[k]));
    // pair z (h=0) with x (h=1): lane ^ 8 has the other plane, same g
    float4 w0 = *(const float4*)(Wout + g * 8);
    float4 w1 = *(const float4*)(Wout + g * 8 + 4);
    float prod = 0.f;
    const float* wp = (const float*)&w0;
#pragma unroll
    for (int k = 0; k < 4; k++) prod = fmaf(t[k] * __shfl_xor(t[k], 8, 64), wp[k], prod);
    wp = (const float*)&w1;
#pragma unroll
    for (int k = 0; k < 4; k++)
        prod = fmaf(t[4 + k] * __shfl_xor(t[4 + k], 8, 64), wp[k], prod);
    for (int o = 4; o >= 1; o >>= 1) prod += __shfl_xor(prod, o, 64);
    if (lane == 0) out[i] = prod + bout[0];
}

// ---------------------------------------------------------------------------

extern "C" void kernel_launch(void* const* d_in, const int* in_sizes, int n_in,
                              void* d_out, int out_size, void* d_ws, size_t ws_size,
                              hipStream_t stream) {
    const float* z = (const float*)d_in[0];
    const float* x = (const float*)d_in[1];
    const int* ei = (const int*)d_in[2];
    const float* We1 = (const float*)d_in[3];
    const float* be1 = (const float*)d_in[4];
    const float* We2 = (const float*)d_in[5];
    const float* be2 = (const float*)d_in[6];
    const float* Wf1 = (const float*)d_in[7];
    const float* bf1 = (const float*)d_in[8];
    const float* Wf2 = (const float*)d_in[9];
    const float* bf2 = (const float*)d_in[10];
    const float* Wout = (const float*)d_in[11];
    const float* bout = (const float*)d_in[12];
    float* out = (float*)d_out;

    int N = in_sizes[0] / 128;
    int E = in_sizes[2] / 2;
    const int* src = ei;
    const int* dst = ei + E;

    char* base = (char*)d_ws;
    size_t off = 0;
    auto take = [&](size_t nbytes) -> char* {
        char* p = base + off;
        off = (off + nbytes + 255) & ~(size_t)255;
        return p;
    };
    int NB = (N + 255) / 256;
    int* cnt = (int*)take((size_t)N * 4);
    int* bsum = (int*)take(1024 * 4);
    int* boff = (int*)take(1024 * 4);
    int* rowp = (int*)take(((size_t)N + 1) * 4);
    float* dinv = (float*)take((size_t)N * 4);
    int* rank = (int*)take((size_t)E * 4);
    int* csrc = (int*)take((size_t)E * 4);
    __half* Hh = (__half*)take((size_t)N * 128 * 2);  // interleaved [N][128]
    __half* azh = (__half*)take((size_t)N * 64 * 2);
    __half* axh = (__half*)take((size_t)N * 64 * 2);

    int egrid = (E + 255) / 256;
    k_zero<<<NB, 256, 0, stream>>>(cnt, N);
    k_deg<<<egrid, 256, 0, stream>>>(dst, E, cnt, rank);
    k_scan1<<<NB, 256, 0, stream>>>(cnt, N, bsum);
    k_scan2<<<1, 256, 0, stream>>>(bsum, NB, boff, rowp, N, E);
    k_scan3<<<NB, 256, 0, stream>>>(cnt, boff, N, rowp, dinv);
    k_fill<<<egrid, 256, 0, stream>>>(src, dst, rank, E, rowp, csrc);

    dim3 mmgrid((N + 63) / 64, 2);
    int agrid = (N + 3) / 4;

    k_mm1<<<mmgrid, 256, 0, stream>>>(z, x, We1, Wf1, dinv, Hh, N);
    k_agg_act<<<agrid, 256, 0, stream>>>(rowp, csrc, dinv, Hh, N, be1, bf1, azh, axh);
    k_mm2h<<<mmgrid, 256, 0, stream>>>(azh, axh, We2, Wf2, dinv, Hh, N);
    k_agg_final<<<agrid, 256, 0, stream>>>(rowp, csrc, dinv, Hh, N, be2, bf2, Wout,
                                           bout, out);
}